// Round 3
// baseline (1267.460 us; speedup 1.0000x reference)
//
#include <hip/hip_runtime.h>

#define NN 100000            // nodes
#define NE 1200000           // edges
#define NRR 400000           // N*R segments
#define NBUK 3125            // buckets of 128 segments: ceil(NRR/128)
#define GGRP 104             // blocks per XCD-group in bucket_scatter (grid = 8*GGRP)

typedef float f32x4 __attribute__((ext_vector_type(4)));
typedef __bf16 bf16x4 __attribute__((ext_vector_type(4)));
typedef __bf16 bf16x8 __attribute__((ext_vector_type(8)));

__device__ __forceinline__ float sigmoidf_(float x){ return 1.0f/(1.0f+__expf(-x)); }

// ---------------- bucket histogram (LDS pre-aggregated) ----------------
__global__ __launch_bounds__(1024)
void bhist_kernel(const int* __restrict__ dst, const int* __restrict__ rel,
                  int* __restrict__ bcnt){
  __shared__ int lh[NBUK];
  int t = threadIdx.x;
  for (int i = t; i < NBUK; i += 1024) lh[i] = 0;
  __syncthreads();
  for (int e = blockIdx.x*1024 + t; e < NE; e += 128*1024){
    int b = (dst[e]*4 + rel[e]) >> 7;
    atomicAdd(&lh[b], 1);
  }
  __syncthreads();
  for (int i = t; i < NBUK; i += 1024)
    if (lh[i]) atomicAdd(&bcnt[i], lh[i]);
}

// ---------------- single-block exclusive scan of bucket counts ----------------
__global__ __launch_bounds__(256)
void bscan_kernel(const int* __restrict__ bcnt, int* __restrict__ boff,
                  int* __restrict__ bcursor){
  __shared__ int tsum[256];
  int t = threadIdx.x;
  int base = t*13;                    // 256*13 = 3328 >= NBUK
  int loc[13]; int s = 0;
  #pragma unroll
  for (int i = 0; i < 13; ++i){
    int idx = base + i;
    int c = (idx < NBUK) ? bcnt[idx] : 0;
    loc[i] = s; s += c;
  }
  tsum[t] = s;
  __syncthreads();
  for (int o = 1; o < 256; o <<= 1){
    int v = tsum[t];
    int u = (t >= o) ? tsum[t-o] : 0;
    __syncthreads();
    tsum[t] = v + u;
    __syncthreads();
  }
  int tb = (t == 0) ? 0 : tsum[t-1];
  #pragma unroll
  for (int i = 0; i < 13; ++i){
    int idx = base + i;
    if (idx < NBUK){ int o = tb + loc[i]; boff[idx] = o; bcursor[idx] = o; }
  }
}

// ---------------- bucket scatter, XCD-partitioned ----------------
// group g = blockIdx&7 writes only buckets [g*391, (g+1)*391): with round-robin
// block->XCD dispatch each ebuck line is written by one XCD -> full-line writebacks.
__global__ __launch_bounds__(256)
void bucket_scatter_kernel(const int* __restrict__ src, const int* __restrict__ dst,
                           const int* __restrict__ rel, int* __restrict__ bcursor,
                           uint2* __restrict__ ebuck){
  int g  = blockIdx.x & 7;
  int bi = blockIdx.x >> 3;
  int lo = g*391, hi = min(lo + 391, NBUK);
  for (int e = bi*256 + (int)threadIdx.x; e < NE; e += GGRP*256){
    int seg = dst[e]*4 + rel[e];
    int b = seg >> 7;
    if (b >= lo && b < hi){
      int p = atomicAdd(&bcursor[b], 1);
      uint2 v; v.x = (unsigned)src[e]; v.y = (unsigned)seg;
      ebuck[p] = v;
    }
  }
}

// ---------------- gather-mean: one block per bucket, LDS accumulators ----------------
__global__ __launch_bounds__(256)
void gather_kernel(const __bf16* __restrict__ xb, const uint2* __restrict__ ebuck,
                   const int* __restrict__ boff, __bf16* __restrict__ segb){
  __shared__ float acc[128*64];     // 32 KB
  __shared__ int   lcnt[128];
  int b = blockIdx.x;
  int t = threadIdx.x;
  #pragma unroll
  for (int i = 0; i < 8; ++i) *(f32x4*)(&acc[(i*256 + t)*4]) = f32x4{0.f,0.f,0.f,0.f};
  if (t < 128) lcnt[t] = 0;
  __syncthreads();

  int e0 = boff[b];
  int e1 = (b+1 < NBUK) ? boff[b+1] : NE;
  int lane = t & 63, wv = t >> 6;
  for (int e = e0 + wv; e < e1; e += 4){
    uint2 v = ebuck[e];
    int s    = (int)v.x;
    int segl = (int)v.y & 127;
    if (lane == 0) atomicAdd(&lcnt[segl], 1);
    float val = (float)xb[(size_t)s*64 + lane];
    atomicAdd(&acc[segl*64 + lane], val);
  }
  __syncthreads();

  // scaled bf16 write: 128 segs x 64 feats, contiguous from seg base b*128
  size_t gbase = (size_t)b * 128 * 64;
  #pragma unroll
  for (int i = 0; i < 4; ++i){
    int idx = (i*256 + t)*8;          // flat offset into [128][64]
    int segl = idx >> 6;
    float inv = 1.0f / fmaxf((float)lcnt[segl], 1.0f);
    f32x4 a = *(const f32x4*)(&acc[idx]);
    f32x4 c = *(const f32x4*)(&acc[idx+4]);
    bf16x8 r;
    r[0]=(__bf16)(a[0]*inv); r[1]=(__bf16)(a[1]*inv);
    r[2]=(__bf16)(a[2]*inv); r[3]=(__bf16)(a[3]*inv);
    r[4]=(__bf16)(c[0]*inv); r[5]=(__bf16)(c[1]*inv);
    r[6]=(__bf16)(c[2]*inv); r[7]=(__bf16)(c[3]*inv);
    *(bf16x8*)(&segb[gbase + idx]) = r;
  }
}

// ---------------- conversions / weight prep ----------------
__global__ void tobf16_kernel(const float* __restrict__ xf, __bf16* __restrict__ xb){
  int i = (blockIdx.x*256 + threadIdx.x)*8;
  if (i < NN*64){
    f32x4 a = *(const f32x4*)(xf + i);
    f32x4 b = *(const f32x4*)(xf + i + 4);
    bf16x8 r;
    r[0]=(__bf16)a[0]; r[1]=(__bf16)a[1]; r[2]=(__bf16)a[2]; r[3]=(__bf16)a[3];
    r[4]=(__bf16)b[0]; r[5]=(__bf16)b[1]; r[6]=(__bf16)b[2]; r[7]=(__bf16)b[3];
    *(bf16x8*)(xb + i) = r;
  }
}

// W1=[w|ws] (64 x 320), W2=[pw;tw] (128 x 128), bias1=b+bs, bias2=[pb|tb]
__global__ void prep_kernel(const float* __restrict__ w,  const float* __restrict__ b,
                            const float* __restrict__ ws, const float* __restrict__ bs,
                            const float* __restrict__ pw, const float* __restrict__ pb,
                            const float* __restrict__ tw, const float* __restrict__ tb,
                            __bf16* __restrict__ W1, __bf16* __restrict__ W2,
                            float* __restrict__ bias1, float* __restrict__ bias2){
  int i = blockIdx.x*256 + threadIdx.x;
  if (i < 64*320) {
    int n = i/320, k = i - n*320;
    float v = (k < 256) ? w[n*256+k] : ws[n*64 + (k-256)];
    W1[i] = (__bf16)v;
  }
  if (i < 128*128) {
    int n = i >> 7, k = i & 127;
    float v = (n < 64) ? pw[n*128+k] : tw[(n-64)*128+k];
    W2[i] = (__bf16)v;
  }
  if (i < 64)  bias1[i] = b[i] + bs[i];
  if (i < 128) bias2[i] = (i < 64) ? pb[i] : tb[i-64];
}

// ---------------- fused dense + highway ----------------
// Block = 128 nodes (two 64-row halves), 4 waves, 16x16x32 bf16 MFMA.
#define W2P 136   // LDS pitch (bf16) for W2
#define HSP 72    // LDS pitch (bf16) for h staging

template<bool LAYER1>
__global__ __launch_bounds__(256)
void dense_kernel(const __bf16* __restrict__ segb,  // [N*R,64] bf16 means
                  const __bf16* __restrict__ xinb,  // [N,64] conv self input
                  const __bf16* __restrict__ prevb, // [N,64] highway prev
                  const __bf16* __restrict__ W1,    // [64][320]
                  const __bf16* __restrict__ W2,    // [128][128]
                  const float* __restrict__ bias1,  // [64]
                  const float* __restrict__ bias2,  // [128]
                  __bf16* __restrict__ hb,          // layer1: conv out (bf16)
                  __bf16* __restrict__ gb,          // layer1: highway out (bf16)
                  float* __restrict__ outp)         // layer2: final fp32
{
  __shared__ __bf16 w2s[128*W2P];
  __shared__ __bf16 hs[128*HSP];

  const int tid = threadIdx.x;
  #pragma unroll
  for (int i = 0; i < 8; ++i) {
    int idx = i*2048 + tid*8;
    int n = idx >> 7, k = idx & 127;
    *(bf16x8*)(&w2s[n*W2P + k]) = *(const bf16x8*)(&W2[idx]);
  }
  __syncthreads();

  const int lane = tid & 63;
  const int wv   = tid >> 6;
  const int mloc = lane & 15;   // A-row / B-col within 16-tile
  const int kg   = lane >> 4;   // k-group
  const int base = blockIdx.x * 128;

  int arow[2];
  arow[0] = min(base      + wv*16 + mloc, NN-1);
  arow[1] = min(base + 64 + wv*16 + mloc, NN-1);

  f32x4 acc1[2][4] = {};

  // GEMM1 part 1: K = 0..256 from segb (upd)
  #pragma unroll
  for (int kb = 0; kb < 256; kb += 32) {
    bf16x8 bf[4];
    #pragma unroll
    for (int j = 0; j < 4; ++j)
      bf[j] = *(const bf16x8*)(&W1[(j*16 + mloc)*320 + kb + kg*8]);
    #pragma unroll
    for (int h = 0; h < 2; ++h) {
      bf16x8 af = *(const bf16x8*)(&segb[(size_t)arow[h]*256 + kb + kg*8]);
      #pragma unroll
      for (int j = 0; j < 4; ++j)
        acc1[h][j] = __builtin_amdgcn_mfma_f32_16x16x32_bf16(af, bf[j], acc1[h][j], 0,0,0);
    }
  }
  // GEMM1 part 2: K = 256..320 from xinb (self loop)
  #pragma unroll
  for (int kb = 0; kb < 64; kb += 32) {
    bf16x8 bf[4];
    #pragma unroll
    for (int j = 0; j < 4; ++j)
      bf[j] = *(const bf16x8*)(&W1[(j*16 + mloc)*320 + 256 + kb + kg*8]);
    #pragma unroll
    for (int h = 0; h < 2; ++h) {
      bf16x8 af = *(const bf16x8*)(&xinb[(size_t)arow[h]*64 + kb + kg*8]);
      #pragma unroll
      for (int j = 0; j < 4; ++j)
        acc1[h][j] = __builtin_amdgcn_mfma_f32_16x16x32_bf16(af, bf[j], acc1[h][j], 0,0,0);
    }
  }

  // epilogue 1: h = sigmoid(acc + bias1); stage bf16 in LDS (wave-private rows)
  #pragma unroll
  for (int h = 0; h < 2; ++h) {
    #pragma unroll
    for (int j = 0; j < 4; ++j) {
      int col = j*16 + mloc;
      float b1 = bias1[col];
      #pragma unroll
      for (int r = 0; r < 4; ++r) {
        float hv = sigmoidf_(acc1[h][j][r] + b1);
        acc1[h][j][r] = hv;
        int trow = h*64 + wv*16 + kg*4 + r;
        hs[trow*HSP + col] = (__bf16)hv;
        if (LAYER1) {
          int grow = base + trow;
          if (grow < NN) hb[(size_t)grow*64 + col] = (__bf16)hv;
        }
      }
    }
  }

  f32x4 acc2[2][8] = {};
  // GEMM2 part 1: K = 0..64 -> c = h (from LDS)
  #pragma unroll
  for (int kb = 0; kb < 64; kb += 32) {
    bf16x8 af[2];
    #pragma unroll
    for (int h = 0; h < 2; ++h) {
      int trow = h*64 + wv*16 + mloc;
      af[h] = *(const bf16x8*)(&hs[trow*HSP + kb + kg*8]);
    }
    #pragma unroll
    for (int j = 0; j < 8; ++j) {
      bf16x8 bf = *(const bf16x8*)(&w2s[(j*16 + mloc)*W2P + kb + kg*8]);
      #pragma unroll
      for (int h = 0; h < 2; ++h)
        acc2[h][j] = __builtin_amdgcn_mfma_f32_16x16x32_bf16(af[h], bf, acc2[h][j], 0,0,0);
    }
  }
  // GEMM2 part 2: K = 64..128 -> c = prev (global bf16)
  #pragma unroll
  for (int kb = 0; kb < 64; kb += 32) {
    bf16x8 af[2];
    #pragma unroll
    for (int h = 0; h < 2; ++h)
      af[h] = *(const bf16x8*)(&prevb[(size_t)arow[h]*64 + kb + kg*8]);
    #pragma unroll
    for (int j = 0; j < 8; ++j) {
      bf16x8 bf = *(const bf16x8*)(&w2s[(j*16 + mloc)*W2P + 64 + kb + kg*8]);
      #pragma unroll
      for (int h = 0; h < 2; ++h)
        acc2[h][j] = __builtin_amdgcn_mfma_f32_16x16x32_bf16(af[h], bf, acc2[h][j], 0,0,0);
    }
  }

  // epilogue 2: pr = relu(.+pb), g = sigmoid(.+tb), out = g*pr + (1-g)*h
  #pragma unroll
  for (int h = 0; h < 2; ++h) {
    #pragma unroll
    for (int j = 0; j < 4; ++j) {
      int col = j*16 + mloc;
      float bp = bias2[col];
      float bt = bias2[64 + col];
      #pragma unroll
      for (int r = 0; r < 4; ++r) {
        float pr = fmaxf(acc2[h][j][r] + bp, 0.0f);
        float g  = sigmoidf_(acc2[h][j+4][r] + bt);
        float hv = acc1[h][j][r];
        float ov = g*pr + (1.0f - g)*hv;
        int grow = base + h*64 + wv*16 + kg*4 + r;
        if (grow < NN) {
          if (LAYER1) gb[(size_t)grow*64 + col] = (__bf16)ov;
          else        outp[(size_t)grow*64 + col] = ov;
        }
      }
    }
  }
}

extern "C" void kernel_launch(void* const* d_in, const int* in_sizes, int n_in,
                              void* d_out, int out_size, void* d_ws, size_t ws_size,
                              hipStream_t stream){
  const float* x    = (const float*)d_in[0];
  const int*   src  = (const int*)d_in[1];
  const int*   dst  = (const int*)d_in[2];
  const int*   rel  = (const int*)d_in[3];
  const float* c1w  = (const float*)d_in[4];
  const float* c1b  = (const float*)d_in[5];
  const float* c1ws = (const float*)d_in[6];
  const float* c1bs = (const float*)d_in[7];
  const float* h1pw = (const float*)d_in[8];
  const float* h1pb = (const float*)d_in[9];
  const float* h1tw = (const float*)d_in[10];
  const float* h1tb = (const float*)d_in[11];
  const float* c2w  = (const float*)d_in[12];
  const float* c2b  = (const float*)d_in[13];
  const float* c2ws = (const float*)d_in[14];
  const float* c2bs = (const float*)d_in[15];
  const float* h2pw = (const float*)d_in[16];
  const float* h2pb = (const float*)d_in[17];
  const float* h2tw = (const float*)d_in[18];
  const float* h2tb = (const float*)d_in[19];

  char* p = (char*)d_ws;
  __bf16* segb = (__bf16*)p;  p += (size_t)NRR*64*2;
  __bf16* xb   = (__bf16*)p;  p += (size_t)NN*64*2;
  __bf16* h1b  = (__bf16*)p;  p += (size_t)NN*64*2;
  __bf16* g1b  = (__bf16*)p;  p += (size_t)NN*64*2;
  uint2* ebuck = (uint2*)p;   p += (size_t)NE*8;
  int* bcnt    = (int*)p;     p += 3200*4;
  int* boff    = (int*)p;     p += 3200*4;
  int* bcursor = (int*)p;     p += 3200*4;
  __bf16* W1a  = (__bf16*)p;  p += 64*320*2;
  __bf16* W2a  = (__bf16*)p;  p += 128*128*2;
  __bf16* W1b  = (__bf16*)p;  p += 64*320*2;
  __bf16* W2b  = (__bf16*)p;  p += 128*128*2;
  float* B1a   = (float*)p;   p += 64*4;
  float* B2a   = (float*)p;   p += 128*4;
  float* B1b   = (float*)p;   p += 64*4;
  float* B2b   = (float*)p;   p += 128*4;

  float* out = (float*)d_out;

  // bucketed counting sort of edges (shared by both layers)
  hipMemsetAsync(bcnt, 0, 3200*4, stream);
  bhist_kernel<<<128, 1024, 0, stream>>>(dst, rel, bcnt);
  bscan_kernel<<<1, 256, 0, stream>>>(bcnt, boff, bcursor);
  bucket_scatter_kernel<<<8*GGRP, 256, 0, stream>>>(src, dst, rel, bcursor, ebuck);

  tobf16_kernel<<<(NN*64/8 + 255)/256, 256, 0, stream>>>(x, xb);
  prep_kernel<<<80, 256, 0, stream>>>(c1w, c1b, c1ws, c1bs, h1pw, h1pb, h1tw, h1tb,
                                      W1a, W2a, B1a, B2a);
  prep_kernel<<<80, 256, 0, stream>>>(c2w, c2b, c2ws, c2bs, h2pw, h2pb, h2tw, h2tb,
                                      W1b, W2b, B1b, B2b);

  // layer 1
  gather_kernel<<<NBUK, 256, 0, stream>>>(xb, ebuck, boff, segb);
  dense_kernel<true><<<(NN+127)/128, 256, 0, stream>>>(segb, xb, xb, W1a, W2a, B1a, B2a,
                                                       h1b, g1b, nullptr);
  // layer 2
  gather_kernel<<<NBUK, 256, 0, stream>>>(g1b, ebuck, boff, segb);
  dense_kernel<false><<<(NN+127)/128, 256, 0, stream>>>(segb, g1b, h1b, W1b, W2b, B1b, B2b,
                                                        nullptr, nullptr, out);
}

// Round 4
// 531.417 us; speedup vs baseline: 2.3851x; 2.3851x over previous
//
#include <hip/hip_runtime.h>

#define NN 100000            // nodes
#define NE 1200000           // edges
#define NRR 400000           // N*R segments
#define NBUK 3125            // buckets of 128 segs (= exactly 32 nodes); 3125*128 == NRR
#define GGRP 104             // blocks per XCD-group in bucket_scatter (grid = 8*GGRP)
#define SSZ 1280             // per-bucket edge capacity in LDS (mean 384, sigma ~20)

typedef float f32x4 __attribute__((ext_vector_type(4)));
typedef __bf16 bf16x4 __attribute__((ext_vector_type(4)));
typedef __bf16 bf16x8 __attribute__((ext_vector_type(8)));

__device__ __forceinline__ float sigmoidf_(float x){ return 1.0f/(1.0f+__expf(-x)); }

// ---------------- bucket histogram (LDS pre-aggregated) ----------------
__global__ __launch_bounds__(1024)
void bhist_kernel(const int* __restrict__ dst, const int* __restrict__ rel,
                  int* __restrict__ bcnt){
  __shared__ int lh[NBUK];
  int t = threadIdx.x;
  for (int i = t; i < NBUK; i += 1024) lh[i] = 0;
  __syncthreads();
  for (int e = blockIdx.x*1024 + t; e < NE; e += 128*1024){
    int b = (dst[e]*4 + rel[e]) >> 7;
    atomicAdd(&lh[b], 1);
  }
  __syncthreads();
  for (int i = t; i < NBUK; i += 1024)
    if (lh[i]) atomicAdd(&bcnt[i], lh[i]);
}

// ---------------- single-block exclusive scan of bucket counts ----------------
__global__ __launch_bounds__(256)
void bscan_kernel(const int* __restrict__ bcnt, int* __restrict__ boff,
                  int* __restrict__ bcursor){
  __shared__ int tsum[256];
  int t = threadIdx.x;
  int base = t*13;                    // 256*13 = 3328 >= NBUK
  int loc[13]; int s = 0;
  #pragma unroll
  for (int i = 0; i < 13; ++i){
    int idx = base + i;
    int c = (idx < NBUK) ? bcnt[idx] : 0;
    loc[i] = s; s += c;
  }
  tsum[t] = s;
  __syncthreads();
  for (int o = 1; o < 256; o <<= 1){
    int v = tsum[t];
    int u = (t >= o) ? tsum[t-o] : 0;
    __syncthreads();
    tsum[t] = v + u;
    __syncthreads();
  }
  int tb = (t == 0) ? 0 : tsum[t-1];
  #pragma unroll
  for (int i = 0; i < 13; ++i){
    int idx = base + i;
    if (idx < NBUK){ int o = tb + loc[i]; boff[idx] = o; bcursor[idx] = o; }
  }
  if (t == 0) boff[NBUK] = NE;        // sentinel
}

// ---------------- bucket scatter, XCD-partitioned, packed u32 ----------------
// group g = blockIdx&7 writes only buckets [g*391, (g+1)*391): each ebuck line is
// written by one XCD -> full-line writebacks. Entry = src | (local_seg << 17).
__global__ __launch_bounds__(256)
void bucket_scatter_kernel(const int* __restrict__ src, const int* __restrict__ dst,
                           const int* __restrict__ rel, int* __restrict__ bcursor,
                           unsigned* __restrict__ ebuck){
  int g  = blockIdx.x & 7;
  int bi = blockIdx.x >> 3;
  int lo = g*391, hi = min(lo + 391, NBUK);
  for (int e = bi*256 + (int)threadIdx.x; e < NE; e += GGRP*256){
    int seg = dst[e]*4 + rel[e];
    int b = seg >> 7;
    if (b >= lo && b < hi){
      int p = atomicAdd(&bcursor[b], 1);
      ebuck[p] = (unsigned)src[e] | ((unsigned)(seg & 127) << 17);
    }
  }
}

// ---------------- conversions / weight prep ----------------
__global__ void tobf16_kernel(const float* __restrict__ xf, __bf16* __restrict__ xb){
  int i = (blockIdx.x*256 + threadIdx.x)*8;
  if (i < NN*64){
    f32x4 a = *(const f32x4*)(xf + i);
    f32x4 b = *(const f32x4*)(xf + i + 4);
    bf16x8 r;
    r[0]=(__bf16)a[0]; r[1]=(__bf16)a[1]; r[2]=(__bf16)a[2]; r[3]=(__bf16)a[3];
    r[4]=(__bf16)b[0]; r[5]=(__bf16)b[1]; r[6]=(__bf16)b[2]; r[7]=(__bf16)b[3];
    *(bf16x8*)(xb + i) = r;
  }
}

// W1=[w|ws] (64 x 320), W2=[pw;tw] (128 x 128), bias1=b+bs, bias2=[pb|tb]
__global__ void prep_kernel(const float* __restrict__ w,  const float* __restrict__ b,
                            const float* __restrict__ ws, const float* __restrict__ bs,
                            const float* __restrict__ pw, const float* __restrict__ pb,
                            const float* __restrict__ tw, const float* __restrict__ tb,
                            __bf16* __restrict__ W1, __bf16* __restrict__ W2,
                            float* __restrict__ bias1, float* __restrict__ bias2){
  int i = blockIdx.x*256 + threadIdx.x;
  if (i < 64*320) {
    int n = i/320, k = i - n*320;
    float v = (k < 256) ? w[n*256+k] : ws[n*64 + (k-256)];
    W1[i] = (__bf16)v;
  }
  if (i < 128*128) {
    int n = i >> 7, k = i & 127;
    float v = (n < 64) ? pw[n*128+k] : tw[(n-64)*128+k];
    W2[i] = (__bf16)v;
  }
  if (i < 64)  bias1[i] = b[i] + bs[i];
  if (i < 128) bias2[i] = (i < 64) ? pb[i] : tb[i-64];
}

// ---------------- fused: local sort + gather-mean + GEMM1 + GEMM2 ----------------
// One block per bucket = 128 segments = 32 nodes. 256 threads (4 waves).
//   Phase S: in-LDS counting sort of the bucket's edges by local segment.
//   Phase G: 16 lanes/segment register-accumulated mean -> bf16 LDS "am" = A operand.
//   Phase M: GEMM1 [32x320]@W1^T -> sigmoid -> h (LDS + optional global)
//            GEMM2 [h|prev]@W2^T -> highway -> output. No segb materialization.
#define AMP 264   // am pitch (bf16): 264*2B=528B -> bank start 4*(mloc+kg)%32, balanced
#define HSP 72    // hstage pitch

template<bool LAYER1>
__global__ __launch_bounds__(256)
void fused_kernel(const unsigned* __restrict__ ebuck, const int* __restrict__ boff,
                  const __bf16* __restrict__ inb,    // conv input: gather source + self rows
                  const __bf16* __restrict__ prevb,  // highway prev rows
                  const __bf16* __restrict__ W1,     // [64][320]
                  const __bf16* __restrict__ W2,     // [128][128]
                  const float* __restrict__ bias1,   // [64]
                  const float* __restrict__ bias2,   // [128]
                  __bf16* __restrict__ hb,           // layer1: conv out
                  __bf16* __restrict__ gb,           // layer1: highway out
                  float* __restrict__ outp)          // layer2: final fp32
{
  __shared__ int lcnt[128], lscan[128], lcur[128];
  __shared__ int ssrc[SSZ];
  __shared__ __bf16 am[32*AMP];       // ~16.9 KB means / A-operand [32 nodes][256], padded
  __shared__ __bf16 hstage[32*HSP];   // 4.6 KB

  const int b = blockIdx.x;
  const int t = threadIdx.x;
  const int e0 = boff[b], e1 = boff[b+1];

  // ---- Phase S: counting sort by local seg ----
  if (t < 128) lcnt[t] = 0;
  __syncthreads();
  for (int e = e0 + t; e < e1; e += 256){
    unsigned v = ebuck[e];
    atomicAdd(&lcnt[(v >> 17) & 127], 1);
  }
  __syncthreads();
  if (t < 128) lscan[t] = lcnt[t];
  __syncthreads();
  for (int o = 1; o < 128; o <<= 1){
    int v = 0;
    if (t < 128){ v = lscan[t]; if (t >= o) v += lscan[t-o]; }
    __syncthreads();
    if (t < 128) lscan[t] = v;
    __syncthreads();
  }
  if (t < 128) lcur[t] = (t == 0) ? 0 : lscan[t-1];
  __syncthreads();
  for (int e = e0 + t; e < e1; e += 256){
    unsigned v = ebuck[e];
    int sl = (v >> 17) & 127;
    int p = atomicAdd(&lcur[sl], 1);
    if (p < SSZ) ssrc[p] = (int)(v & 0x1FFFFu);
  }
  __syncthreads();
  // now lcur[sl] = end offset, lcnt[sl] = count

  // ---- Phase G: register-accumulated means ----
  {
    const int fl = t & 15;
    for (int sp = 0; sp < 8; ++sp){
      int sl = sp*16 + (t >> 4);
      int c = lcnt[sl];
      int oo = lcur[sl] - c;
      f32x4 a = {0.f, 0.f, 0.f, 0.f};
      for (int i = 0; i < c; ++i){
        int s = ssrc[oo + i];
        bf16x4 v = *(const bf16x4*)(&inb[(size_t)s*64 + fl*4]);
        a[0] += (float)v[0]; a[1] += (float)v[1];
        a[2] += (float)v[2]; a[3] += (float)v[3];
      }
      float inv = 1.0f / fmaxf((float)c, 1.0f);
      bf16x4 r;
      r[0]=(__bf16)(a[0]*inv); r[1]=(__bf16)(a[1]*inv);
      r[2]=(__bf16)(a[2]*inv); r[3]=(__bf16)(a[3]*inv);
      // seg sl -> node row sl>>2, K offset (sl&3)*64
      *(bf16x4*)(&am[(sl>>2)*AMP + (sl&3)*64 + fl*4]) = r;
    }
  }
  __syncthreads();

  // ---- Phase M: MFMA ----
  const int lane = t & 63;
  const int wv   = t >> 6;
  const int mloc = lane & 15;
  const int kg   = lane >> 4;
  const int mt   = wv & 1;        // m-tile (16 rows)
  const int nh   = wv >> 1;       // column half
  const int arowL = mt*16 + mloc; // local A row 0..31
  const size_t nodeA = (size_t)(b*32 + arowL);

  f32x4 acc1[2] = {};             // GEMM1 n-tiles nh*2, nh*2+1
  #pragma unroll
  for (int kb = 0; kb < 256; kb += 32){
    bf16x8 af = *(const bf16x8*)(&am[arowL*AMP + kb + kg*8]);
    #pragma unroll
    for (int jj = 0; jj < 2; ++jj){
      int j = nh*2 + jj;
      bf16x8 bf = *(const bf16x8*)(&W1[(j*16 + mloc)*320 + kb + kg*8]);
      acc1[jj] = __builtin_amdgcn_mfma_f32_16x16x32_bf16(af, bf, acc1[jj], 0,0,0);
    }
  }
  #pragma unroll
  for (int kb = 0; kb < 64; kb += 32){     // self-loop K=256..320
    bf16x8 af = *(const bf16x8*)(&inb[nodeA*64 + kb + kg*8]);
    #pragma unroll
    for (int jj = 0; jj < 2; ++jj){
      int j = nh*2 + jj;
      bf16x8 bf = *(const bf16x8*)(&W1[(j*16 + mloc)*320 + 256 + kb + kg*8]);
      acc1[jj] = __builtin_amdgcn_mfma_f32_16x16x32_bf16(af, bf, acc1[jj], 0,0,0);
    }
  }

  // epilogue 1: h = sigmoid(acc + bias1)
  #pragma unroll
  for (int jj = 0; jj < 2; ++jj){
    int col = nh*32 + jj*16 + mloc;
    float b1 = bias1[col];
    #pragma unroll
    for (int r = 0; r < 4; ++r){
      float hv = sigmoidf_(acc1[jj][r] + b1);
      acc1[jj][r] = hv;
      int hrow = mt*16 + kg*4 + r;
      hstage[hrow*HSP + col] = (__bf16)hv;
      if (LAYER1) hb[(size_t)(b*32 + hrow)*64 + col] = (__bf16)hv;
    }
  }
  __syncthreads();

  f32x4 acc2[4] = {};   // q<2: pr tiles nh*2+q ; q>=2: g tiles 4+nh*2+(q-2)
  #pragma unroll
  for (int kb = 0; kb < 64; kb += 32){     // K 0..64: A = h from LDS
    bf16x8 af = *(const bf16x8*)(&hstage[arowL*HSP + kb + kg*8]);
    #pragma unroll
    for (int q = 0; q < 4; ++q){
      int j = (q < 2) ? (nh*2 + q) : (4 + nh*2 + (q-2));
      bf16x8 bf = *(const bf16x8*)(&W2[(j*16 + mloc)*128 + kb + kg*8]);
      acc2[q] = __builtin_amdgcn_mfma_f32_16x16x32_bf16(af, bf, acc2[q], 0,0,0);
    }
  }
  #pragma unroll
  for (int kb = 0; kb < 64; kb += 32){     // K 64..128: A = prev rows (global)
    bf16x8 af = *(const bf16x8*)(&prevb[nodeA*64 + kb + kg*8]);
    #pragma unroll
    for (int q = 0; q < 4; ++q){
      int j = (q < 2) ? (nh*2 + q) : (4 + nh*2 + (q-2));
      bf16x8 bf = *(const bf16x8*)(&W2[(j*16 + mloc)*128 + 64 + kb + kg*8]);
      acc2[q] = __builtin_amdgcn_mfma_f32_16x16x32_bf16(af, bf, acc2[q], 0,0,0);
    }
  }

  // epilogue 2: highway
  #pragma unroll
  for (int jj = 0; jj < 2; ++jj){
    int col = nh*32 + jj*16 + mloc;
    float bp = bias2[col];
    float bt = bias2[64 + col];
    #pragma unroll
    for (int r = 0; r < 4; ++r){
      float pr = fmaxf(acc2[jj][r] + bp, 0.0f);
      float g  = sigmoidf_(acc2[jj+2][r] + bt);
      float hv = acc1[jj][r];
      float ov = g*pr + (1.0f - g)*hv;
      size_t grow = (size_t)(b*32 + mt*16 + kg*4 + r);
      if (LAYER1) gb[grow*64 + col] = (__bf16)ov;
      else        outp[grow*64 + col] = ov;
    }
  }
}

extern "C" void kernel_launch(void* const* d_in, const int* in_sizes, int n_in,
                              void* d_out, int out_size, void* d_ws, size_t ws_size,
                              hipStream_t stream){
  const float* x    = (const float*)d_in[0];
  const int*   src  = (const int*)d_in[1];
  const int*   dst  = (const int*)d_in[2];
  const int*   rel  = (const int*)d_in[3];
  const float* c1w  = (const float*)d_in[4];
  const float* c1b  = (const float*)d_in[5];
  const float* c1ws = (const float*)d_in[6];
  const float* c1bs = (const float*)d_in[7];
  const float* h1pw = (const float*)d_in[8];
  const float* h1pb = (const float*)d_in[9];
  const float* h1tw = (const float*)d_in[10];
  const float* h1tb = (const float*)d_in[11];
  const float* c2w  = (const float*)d_in[12];
  const float* c2b  = (const float*)d_in[13];
  const float* c2ws = (const float*)d_in[14];
  const float* c2bs = (const float*)d_in[15];
  const float* h2pw = (const float*)d_in[16];
  const float* h2pb = (const float*)d_in[17];
  const float* h2tw = (const float*)d_in[18];
  const float* h2tb = (const float*)d_in[19];

  char* p = (char*)d_ws;
  __bf16* xb   = (__bf16*)p;  p += (size_t)NN*64*2;
  __bf16* h1b  = (__bf16*)p;  p += (size_t)NN*64*2;
  __bf16* g1b  = (__bf16*)p;  p += (size_t)NN*64*2;
  unsigned* ebuck = (unsigned*)p; p += (size_t)NE*4;
  int* bcnt    = (int*)p;     p += 3200*4;
  int* boff    = (int*)p;     p += 3200*4;
  int* bcursor = (int*)p;     p += 3200*4;
  __bf16* W1a  = (__bf16*)p;  p += 64*320*2;
  __bf16* W2a  = (__bf16*)p;  p += 128*128*2;
  __bf16* W1b  = (__bf16*)p;  p += 64*320*2;
  __bf16* W2b  = (__bf16*)p;  p += 128*128*2;
  float* B1a   = (float*)p;   p += 64*4;
  float* B2a   = (float*)p;   p += 128*4;
  float* B1b   = (float*)p;   p += 64*4;
  float* B2b   = (float*)p;   p += 128*4;

  float* out = (float*)d_out;

  // bucketed counting sort of edges (shared by both layers)
  hipMemsetAsync(bcnt, 0, 3200*4, stream);
  bhist_kernel<<<128, 1024, 0, stream>>>(dst, rel, bcnt);
  bscan_kernel<<<1, 256, 0, stream>>>(bcnt, boff, bcursor);
  bucket_scatter_kernel<<<8*GGRP, 256, 0, stream>>>(src, dst, rel, bcursor, ebuck);

  tobf16_kernel<<<(NN*64/8 + 255)/256, 256, 0, stream>>>(x, xb);
  prep_kernel<<<80, 256, 0, stream>>>(c1w, c1b, c1ws, c1bs, h1pw, h1pb, h1tw, h1tb,
                                      W1a, W2a, B1a, B2a);
  prep_kernel<<<80, 256, 0, stream>>>(c2w, c2b, c2ws, c2bs, h2pw, h2pb, h2tw, h2tb,
                                      W1b, W2b, B1b, B2b);

  // layer 1: conv input x, highway prev = x
  fused_kernel<true><<<NBUK, 256, 0, stream>>>(ebuck, boff, xb, xb,
                                               W1a, W2a, B1a, B2a, h1b, g1b, nullptr);
  // layer 2: conv input g1, highway prev = h1
  fused_kernel<false><<<NBUK, 256, 0, stream>>>(ebuck, boff, g1b, h1b,
                                                W1b, W2b, B1b, B2b, nullptr, nullptr, out);
}

// Round 5
// 431.204 us; speedup vs baseline: 2.9393x; 1.2324x over previous
//
#include <hip/hip_runtime.h>

#define NN 100000            // nodes
#define NE 1200000           // edges
#define NRR 400000           // N*R segments
#define NBUK 3125            // buckets of 128 segs (= exactly 32 nodes); 3125*128 == NRR
#define SSZ 1280             // per-bucket edge capacity in LDS (mean 384, max ~480)

typedef float f32x4 __attribute__((ext_vector_type(4)));
typedef __bf16 bf16x4 __attribute__((ext_vector_type(4)));
typedef __bf16 bf16x8 __attribute__((ext_vector_type(8)));

__device__ __forceinline__ float sigmoidf_(float x){ return 1.0f/(1.0f+__expf(-x)); }

// ---------------- bucket histogram (LDS pre-aggregated) ----------------
__global__ __launch_bounds__(1024)
void bhist_kernel(const int* __restrict__ dst, const int* __restrict__ rel,
                  int* __restrict__ bcnt){
  __shared__ int lh[NBUK];
  int t = threadIdx.x;
  for (int i = t; i < NBUK; i += 1024) lh[i] = 0;
  __syncthreads();
  for (int e = blockIdx.x*1024 + t; e < NE; e += 128*1024){
    int b = (dst[e]*4 + rel[e]) >> 7;
    atomicAdd(&lh[b], 1);
  }
  __syncthreads();
  for (int i = t; i < NBUK; i += 1024)
    if (lh[i]) atomicAdd(&bcnt[i], lh[i]);
}

// ---------------- single-block exclusive scan of bucket counts ----------------
__global__ __launch_bounds__(256)
void bscan_kernel(const int* __restrict__ bcnt, int* __restrict__ boff,
                  int* __restrict__ bcursor){
  __shared__ int tsum[256];
  int t = threadIdx.x;
  int base = t*13;                    // 256*13 = 3328 >= NBUK
  int loc[13]; int s = 0;
  #pragma unroll
  for (int i = 0; i < 13; ++i){
    int idx = base + i;
    int c = (idx < NBUK) ? bcnt[idx] : 0;
    loc[i] = s; s += c;
  }
  tsum[t] = s;
  __syncthreads();
  for (int o = 1; o < 256; o <<= 1){
    int v = tsum[t];
    int u = (t >= o) ? tsum[t-o] : 0;
    __syncthreads();
    tsum[t] = v + u;
    __syncthreads();
  }
  int tb = (t == 0) ? 0 : tsum[t-1];
  #pragma unroll
  for (int i = 0; i < 13; ++i){
    int idx = base + i;
    if (idx < NBUK){ int o = tb + loc[i]; boff[idx] = o; bcursor[idx] = o; }
  }
  if (t == 0) boff[NBUK] = NE;        // sentinel
}

// ---------------- single-pass bucket scatter, full grid ----------------
// Within-bucket order is irrelevant (fused kernel sorts locally), so plain
// atomic cursor + scattered u32 write. Entry = src | (local_seg << 17).
__global__ __launch_bounds__(256)
void place_kernel(const int* __restrict__ src, const int* __restrict__ dst,
                  const int* __restrict__ rel, int* __restrict__ bcursor,
                  unsigned* __restrict__ ebuck){
  int e = blockIdx.x*256 + threadIdx.x;
  if (e < NE){
    int seg = dst[e]*4 + rel[e];
    int b = seg >> 7;
    int p = atomicAdd(&bcursor[b], 1);
    ebuck[p] = (unsigned)src[e] | ((unsigned)(seg & 127) << 17);
  }
}

// ---------------- conversions / weight prep ----------------
__global__ void tobf16_kernel(const float* __restrict__ xf, __bf16* __restrict__ xb){
  int i = (blockIdx.x*256 + threadIdx.x)*8;
  if (i < NN*64){
    f32x4 a = *(const f32x4*)(xf + i);
    f32x4 b = *(const f32x4*)(xf + i + 4);
    bf16x8 r;
    r[0]=(__bf16)a[0]; r[1]=(__bf16)a[1]; r[2]=(__bf16)a[2]; r[3]=(__bf16)a[3];
    r[4]=(__bf16)b[0]; r[5]=(__bf16)b[1]; r[6]=(__bf16)b[2]; r[7]=(__bf16)b[3];
    *(bf16x8*)(xb + i) = r;
  }
}

// W1=[w|ws] (64 x 320), W2=[pw;tw] (128 x 128), bias1=b+bs, bias2=[pb|tb]
__global__ void prep_kernel(const float* __restrict__ w,  const float* __restrict__ b,
                            const float* __restrict__ ws, const float* __restrict__ bs,
                            const float* __restrict__ pw, const float* __restrict__ pb,
                            const float* __restrict__ tw, const float* __restrict__ tb,
                            __bf16* __restrict__ W1, __bf16* __restrict__ W2,
                            float* __restrict__ bias1, float* __restrict__ bias2){
  int i = blockIdx.x*256 + threadIdx.x;
  if (i < 64*320) {
    int n = i/320, k = i - n*320;
    float v = (k < 256) ? w[n*256+k] : ws[n*64 + (k-256)];
    W1[i] = (__bf16)v;
  }
  if (i < 128*128) {
    int n = i >> 7, k = i & 127;
    float v = (n < 64) ? pw[n*128+k] : tw[(n-64)*128+k];
    W2[i] = (__bf16)v;
  }
  if (i < 64)  bias1[i] = b[i] + bs[i];
  if (i < 128) bias2[i] = (i < 64) ? pb[i] : tb[i-64];
}

// ---------------- fused: local sort + gather-mean + GEMM1 + GEMM2 ----------------
// One block per bucket = 128 segments = 32 nodes. 256 threads (4 waves).
//   Phase S: edges staged in registers; LDS histogram; wave-0 shuffle scan; place.
//   Phase G: 16 lanes/segment, 2-way unrolled register-accumulated mean -> bf16 "am".
//   Phase M: GEMM1 [32x320]@W1^T -> sigmoid -> h ; GEMM2 [h|prev]@W2^T -> highway.
#define AMP 264   // am pitch (bf16): 528B rows -> 2-way max on ds_read_b128 (free)
#define HSP 72    // hstage pitch

template<bool LAYER1>
__global__ __launch_bounds__(256)
void fused_kernel(const unsigned* __restrict__ ebuck, const int* __restrict__ boff,
                  const __bf16* __restrict__ inb,    // conv input: gather source + self rows
                  const __bf16* __restrict__ prevb,  // highway prev rows
                  const __bf16* __restrict__ W1,     // [64][320]
                  const __bf16* __restrict__ W2,     // [128][128]
                  const float* __restrict__ bias1,   // [64]
                  const float* __restrict__ bias2,   // [128]
                  __bf16* __restrict__ hb,           // layer1: conv out
                  __bf16* __restrict__ gb,           // layer1: highway out
                  float* __restrict__ outp)          // layer2: final fp32
{
  __shared__ int lcnt[128], lcur[128];
  __shared__ __align__(16) char u_mem[SSZ*4];   // 5120B: ssrc (S/G) ∪ hstage (M)
  __shared__ __bf16 am[32*AMP];                 // 16.9 KB means / A-operand [32][256]
  int*    ssrc   = (int*)u_mem;
  __bf16* hstage = (__bf16*)u_mem;              // 32*HSP*2 = 4608B <= 5120B

  const int b = blockIdx.x;
  const int t = threadIdx.x;
  const int e0 = boff[b], e1 = boff[b+1];

  // ---- Phase S: stage edges in regs, histogram, scan, place ----
  unsigned ev[8]; int nk = 0;
  #pragma unroll
  for (int k = 0; k < 8; ++k){
    int e = e0 + t + k*256;
    if (e < e1) ev[nk++] = ebuck[e];
  }
  if (t < 128) lcnt[t] = 0;
  __syncthreads();
  for (int k = 0; k < nk; ++k)
    atomicAdd(&lcnt[(ev[k] >> 17) & 127], 1);
  __syncthreads();
  if (t < 64){                        // wave 0: shuffle-scan 128 counts (2/lane)
    int c0 = lcnt[2*t], c1 = lcnt[2*t+1];
    int s = c0 + c1;
    #pragma unroll
    for (int o = 1; o < 64; o <<= 1){
      int u = __shfl_up(s, o);
      if (t >= o) s += u;
    }
    lcur[2*t]   = s - c1 - c0;        // exclusive starts
    lcur[2*t+1] = s - c1;
  }
  __syncthreads();
  for (int k = 0; k < nk; ++k){
    int sl = (ev[k] >> 17) & 127;
    int p = atomicAdd(&lcur[sl], 1);
    if (p < SSZ) ssrc[p] = (int)(ev[k] & 0x1FFFFu);
  }
  __syncthreads();
  // now lcur[sl] = end offset, lcnt[sl] = count

  // ---- Phase G: register-accumulated means, 2-way unrolled ----
  {
    const int fl  = t & 15;
    const int grp = t >> 4;
    for (int sp = 0; sp < 8; ++sp){
      int sl = sp*16 + grp;
      int c  = lcnt[sl];
      int oo = lcur[sl] - c;
      f32x4 a0 = {0.f,0.f,0.f,0.f}, a1 = {0.f,0.f,0.f,0.f};
      int i = 0;
      for (; i + 2 <= c; i += 2){
        int s0 = ssrc[oo+i], s1 = ssrc[oo+i+1];
        bf16x4 v0 = *(const bf16x4*)(&inb[(size_t)s0*64 + fl*4]);
        bf16x4 v1 = *(const bf16x4*)(&inb[(size_t)s1*64 + fl*4]);
        a0[0]+=(float)v0[0]; a0[1]+=(float)v0[1]; a0[2]+=(float)v0[2]; a0[3]+=(float)v0[3];
        a1[0]+=(float)v1[0]; a1[1]+=(float)v1[1]; a1[2]+=(float)v1[2]; a1[3]+=(float)v1[3];
      }
      if (i < c){
        int s0 = ssrc[oo+i];
        bf16x4 v0 = *(const bf16x4*)(&inb[(size_t)s0*64 + fl*4]);
        a0[0]+=(float)v0[0]; a0[1]+=(float)v0[1]; a0[2]+=(float)v0[2]; a0[3]+=(float)v0[3];
      }
      float inv = 1.0f / fmaxf((float)c, 1.0f);
      bf16x4 r;
      r[0]=(__bf16)((a0[0]+a1[0])*inv); r[1]=(__bf16)((a0[1]+a1[1])*inv);
      r[2]=(__bf16)((a0[2]+a1[2])*inv); r[3]=(__bf16)((a0[3]+a1[3])*inv);
      // seg sl -> node row sl>>2, K offset (sl&3)*64
      *(bf16x4*)(&am[(sl>>2)*AMP + (sl&3)*64 + fl*4]) = r;
    }
  }
  __syncthreads();   // am ready; ssrc dead (hstage may reuse u_mem after this point)

  // ---- Phase M: MFMA ----
  const int lane = t & 63;
  const int wv   = t >> 6;
  const int mloc = lane & 15;
  const int kg   = lane >> 4;
  const int mt   = wv & 1;        // m-tile (16 rows)
  const int nh   = wv >> 1;       // column half
  const int arowL = mt*16 + mloc; // local A row 0..31
  const size_t nodeA = (size_t)(b*32 + arowL);

  f32x4 acc1[2] = {};             // GEMM1 n-tiles nh*2, nh*2+1
  #pragma unroll
  for (int kb = 0; kb < 256; kb += 32){
    bf16x8 af = *(const bf16x8*)(&am[arowL*AMP + kb + kg*8]);
    #pragma unroll
    for (int jj = 0; jj < 2; ++jj){
      int j = nh*2 + jj;
      bf16x8 bf = *(const bf16x8*)(&W1[(j*16 + mloc)*320 + kb + kg*8]);
      acc1[jj] = __builtin_amdgcn_mfma_f32_16x16x32_bf16(af, bf, acc1[jj], 0,0,0);
    }
  }
  #pragma unroll
  for (int kb = 0; kb < 64; kb += 32){     // self-loop K=256..320
    bf16x8 af = *(const bf16x8*)(&inb[nodeA*64 + kb + kg*8]);
    #pragma unroll
    for (int jj = 0; jj < 2; ++jj){
      int j = nh*2 + jj;
      bf16x8 bf = *(const bf16x8*)(&W1[(j*16 + mloc)*320 + 256 + kb + kg*8]);
      acc1[jj] = __builtin_amdgcn_mfma_f32_16x16x32_bf16(af, bf, acc1[jj], 0,0,0);
    }
  }

  // epilogue 1: h = sigmoid(acc + bias1)
  #pragma unroll
  for (int jj = 0; jj < 2; ++jj){
    int col = nh*32 + jj*16 + mloc;
    float b1 = bias1[col];
    #pragma unroll
    for (int r = 0; r < 4; ++r){
      float hv = sigmoidf_(acc1[jj][r] + b1);
      acc1[jj][r] = hv;
      int hrow = mt*16 + kg*4 + r;
      hstage[hrow*HSP + col] = (__bf16)hv;
      if (LAYER1) hb[(size_t)(b*32 + hrow)*64 + col] = (__bf16)hv;
    }
  }
  __syncthreads();

  f32x4 acc2[4] = {};   // q<2: pr tiles nh*2+q ; q>=2: g tiles 4+nh*2+(q-2)
  #pragma unroll
  for (int kb = 0; kb < 64; kb += 32){     // K 0..64: A = h from LDS
    bf16x8 af = *(const bf16x8*)(&hstage[arowL*HSP + kb + kg*8]);
    #pragma unroll
    for (int q = 0; q < 4; ++q){
      int j = (q < 2) ? (nh*2 + q) : (4 + nh*2 + (q-2));
      bf16x8 bf = *(const bf16x8*)(&W2[(j*16 + mloc)*128 + kb + kg*8]);
      acc2[q] = __builtin_amdgcn_mfma_f32_16x16x32_bf16(af, bf, acc2[q], 0,0,0);
    }
  }
  #pragma unroll
  for (int kb = 0; kb < 64; kb += 32){     // K 64..128: A = prev rows (global)
    bf16x8 af = *(const bf16x8*)(&prevb[nodeA*64 + kb + kg*8]);
    #pragma unroll
    for (int q = 0; q < 4; ++q){
      int j = (q < 2) ? (nh*2 + q) : (4 + nh*2 + (q-2));
      bf16x8 bf = *(const bf16x8*)(&W2[(j*16 + mloc)*128 + 64 + kb + kg*8]);
      acc2[q] = __builtin_amdgcn_mfma_f32_16x16x32_bf16(af, bf, acc2[q], 0,0,0);
    }
  }

  // epilogue 2: highway
  #pragma unroll
  for (int jj = 0; jj < 2; ++jj){
    int col = nh*32 + jj*16 + mloc;
    float bp = bias2[col];
    float bt = bias2[64 + col];
    #pragma unroll
    for (int r = 0; r < 4; ++r){
      float pr = fmaxf(acc2[jj][r] + bp, 0.0f);
      float g  = sigmoidf_(acc2[jj+2][r] + bt);
      float hv = acc1[jj][r];
      float ov = g*pr + (1.0f - g)*hv;
      size_t grow = (size_t)(b*32 + mt*16 + kg*4 + r);
      if (LAYER1) gb[grow*64 + col] = (__bf16)ov;
      else        outp[grow*64 + col] = ov;
    }
  }
}

extern "C" void kernel_launch(void* const* d_in, const int* in_sizes, int n_in,
                              void* d_out, int out_size, void* d_ws, size_t ws_size,
                              hipStream_t stream){
  const float* x    = (const float*)d_in[0];
  const int*   src  = (const int*)d_in[1];
  const int*   dst  = (const int*)d_in[2];
  const int*   rel  = (const int*)d_in[3];
  const float* c1w  = (const float*)d_in[4];
  const float* c1b  = (const float*)d_in[5];
  const float* c1ws = (const float*)d_in[6];
  const float* c1bs = (const float*)d_in[7];
  const float* h1pw = (const float*)d_in[8];
  const float* h1pb = (const float*)d_in[9];
  const float* h1tw = (const float*)d_in[10];
  const float* h1tb = (const float*)d_in[11];
  const float* c2w  = (const float*)d_in[12];
  const float* c2b  = (const float*)d_in[13];
  const float* c2ws = (const float*)d_in[14];
  const float* c2bs = (const float*)d_in[15];
  const float* h2pw = (const float*)d_in[16];
  const float* h2pb = (const float*)d_in[17];
  const float* h2tw = (const float*)d_in[18];
  const float* h2tb = (const float*)d_in[19];

  char* p = (char*)d_ws;
  __bf16* xb   = (__bf16*)p;  p += (size_t)NN*64*2;
  __bf16* h1b  = (__bf16*)p;  p += (size_t)NN*64*2;
  __bf16* g1b  = (__bf16*)p;  p += (size_t)NN*64*2;
  unsigned* ebuck = (unsigned*)p; p += (size_t)NE*4;
  int* bcnt    = (int*)p;     p += 3200*4;
  int* boff    = (int*)p;     p += 3200*4;
  int* bcursor = (int*)p;     p += 3200*4;
  __bf16* W1a  = (__bf16*)p;  p += 64*320*2;
  __bf16* W2a  = (__bf16*)p;  p += 128*128*2;
  __bf16* W1b  = (__bf16*)p;  p += 64*320*2;
  __bf16* W2b  = (__bf16*)p;  p += 128*128*2;
  float* B1a   = (float*)p;   p += 64*4;
  float* B2a   = (float*)p;   p += 128*4;
  float* B1b   = (float*)p;   p += 64*4;
  float* B2b   = (float*)p;   p += 128*4;

  float* out = (float*)d_out;

  // bucketed counting sort of edges (shared by both layers)
  hipMemsetAsync(bcnt, 0, 3200*4, stream);
  bhist_kernel<<<128, 1024, 0, stream>>>(dst, rel, bcnt);
  bscan_kernel<<<1, 256, 0, stream>>>(bcnt, boff, bcursor);
  place_kernel<<<(NE+255)/256, 256, 0, stream>>>(src, dst, rel, bcursor, ebuck);

  tobf16_kernel<<<(NN*64/8 + 255)/256, 256, 0, stream>>>(x, xb);
  prep_kernel<<<80, 256, 0, stream>>>(c1w, c1b, c1ws, c1bs, h1pw, h1pb, h1tw, h1tb,
                                      W1a, W2a, B1a, B2a);
  prep_kernel<<<80, 256, 0, stream>>>(c2w, c2b, c2ws, c2bs, h2pw, h2pb, h2tw, h2tb,
                                      W1b, W2b, B1b, B2b);

  // layer 1: conv input x, highway prev = x
  fused_kernel<true><<<NBUK, 256, 0, stream>>>(ebuck, boff, xb, xb,
                                               W1a, W2a, B1a, B2a, h1b, g1b, nullptr);
  // layer 2: conv input g1, highway prev = h1
  fused_kernel<false><<<NBUK, 256, 0, stream>>>(ebuck, boff, g1b, h1b,
                                                W1b, W2b, B1b, B2b, nullptr, nullptr, out);
}

// Round 6
// 373.279 us; speedup vs baseline: 3.3955x; 1.1552x over previous
//
#include <hip/hip_runtime.h>

#define NN 100000            // nodes
#define NE 1200000           // edges
#define NRR 400000           // N*R segments
#define NBUK 3125            // buckets of 128 segs (= exactly 32 nodes); 3125*128 == NRR
#define NBIN 49              // coarse bins of 64 buckets: ceil(3125/64)
#define SSZ 1280             // per-bucket edge capacity in LDS (mean 384, max ~480)

typedef float f32x4 __attribute__((ext_vector_type(4)));
typedef __bf16 bf16x4 __attribute__((ext_vector_type(4)));
typedef __bf16 bf16x8 __attribute__((ext_vector_type(8)));

__device__ __forceinline__ float sigmoidf_(float x){ return 1.0f/(1.0f+__expf(-x)); }

// ---------------- coarse bin histogram (49 bins) ----------------
__global__ __launch_bounds__(256)
void binhist_kernel(const int* __restrict__ dst, const int* __restrict__ rel,
                    int* __restrict__ bincnt){
  __shared__ int h[NBIN];
  int t = threadIdx.x;
  if (t < NBIN) h[t] = 0;
  __syncthreads();
  for (int e = blockIdx.x*256 + t; e < NE; e += 64*256){
    int bin = (dst[e]*4 + rel[e]) >> 13;
    atomicAdd(&h[bin], 1);
  }
  __syncthreads();
  if (t < NBIN && h[t]) atomicAdd(&bincnt[t], h[t]);
}

// ---------------- tiny exclusive scan of 49 bins ----------------
__global__ void binscan_kernel(const int* __restrict__ bincnt, int* __restrict__ bincur){
  if (threadIdx.x == 0){
    int s = 0;
    for (int i = 0; i < NBIN; ++i){ bincur[i] = s; s += bincnt[i]; }
  }
}

// ---------------- pass A: sort edges into 49 bins; also bucket histogram ----------------
// Each block owns an 8192-edge chunk; reserves ONE run per bin (~668 B) so all
// writes to a line come from one block/XCD -> L2 merges to full-line writebacks.
// ebin entry = src | lseg<<17 | bucket_in_bin<<24.
__global__ __launch_bounds__(256)
void passA_kernel(const int* __restrict__ src, const int* __restrict__ dst,
                  const int* __restrict__ rel, int* __restrict__ bincur,
                  int* __restrict__ bcnt, unsigned* __restrict__ ebin){
  __shared__ int h49[NBIN], runbase[NBIN];
  __shared__ int h3125[NBUK];
  int t = threadIdx.x;
  if (t < NBIN) h49[t] = 0;
  for (int i = t; i < NBUK; i += 256) h3125[i] = 0;
  __syncthreads();
  int lo = blockIdx.x*8192, hi = min(lo + 8192, NE);
  for (int e = lo + t; e < hi; e += 256){
    int seg = dst[e]*4 + rel[e];
    atomicAdd(&h49[seg >> 13], 1);
    atomicAdd(&h3125[seg >> 7], 1);
  }
  __syncthreads();
  for (int i = t; i < NBUK; i += 256)
    if (h3125[i]) atomicAdd(&bcnt[i], h3125[i]);
  if (t < NBIN){
    runbase[t] = h49[t] ? atomicAdd(&bincur[t], h49[t]) : 0;
    h49[t] = 0;
  }
  __syncthreads();
  for (int e = lo + t; e < hi; e += 256){
    int seg = dst[e]*4 + rel[e];
    int bin = seg >> 13;
    int p = runbase[bin] + atomicAdd(&h49[bin], 1);
    ebin[p] = (unsigned)src[e] | ((unsigned)(seg & 127) << 17)
                               | ((unsigned)((seg >> 7) & 63) << 24);
  }
}

// ---------------- exclusive scan of 3125 bucket counts ----------------
__global__ __launch_bounds__(256)
void bscan_kernel(const int* __restrict__ bcnt, int* __restrict__ boff,
                  int* __restrict__ bcursor){
  __shared__ int tsum[256];
  int t = threadIdx.x;
  int base = t*13;                    // 256*13 = 3328 >= NBUK
  int loc[13]; int s = 0;
  #pragma unroll
  for (int i = 0; i < 13; ++i){
    int idx = base + i;
    int c = (idx < NBUK) ? bcnt[idx] : 0;
    loc[i] = s; s += c;
  }
  tsum[t] = s;
  __syncthreads();
  for (int o = 1; o < 256; o <<= 1){
    int v = tsum[t];
    int u = (t >= o) ? tsum[t-o] : 0;
    __syncthreads();
    tsum[t] = v + u;
    __syncthreads();
  }
  int tb = (t == 0) ? 0 : tsum[t-1];
  #pragma unroll
  for (int i = 0; i < 13; ++i){
    int idx = base + i;
    if (idx < NBUK){ int o = tb + loc[i]; boff[idx] = o; bcursor[idx] = o; }
  }
  if (t == 0) boff[NBUK] = NE;        // sentinel
}

// ---------------- pass B: within each bin, sort by bucket -> final ebuck ----------------
// 4 chunks per bin; per chunk: 64-bucket LDS histogram, bulk-reserve per-bucket
// runs (~96-400 entries) from bcursor, scatter through L2 (block-local lines).
// ebuck entry = src | lseg<<17.
__global__ __launch_bounds__(256)
void passB_kernel(const unsigned* __restrict__ ebin, const int* __restrict__ boff,
                  int* __restrict__ bcursor, unsigned* __restrict__ ebuck){
  __shared__ int h64[64], rb64[64];
  int bin = blockIdx.x >> 2, ch = blockIdx.x & 3;
  int t = threadIdx.x;
  int b0 = boff[bin*64];
  int b1 = boff[min((bin+1)*64, NBUK)];
  int sz = b1 - b0, csz = (sz + 3) >> 2;
  int lo = b0 + ch*csz, hi = min(lo + csz, b1);
  if (t < 64) h64[t] = 0;
  __syncthreads();
  for (int e = lo + t; e < hi; e += 256)
    atomicAdd(&h64[(ebin[e] >> 24) & 63], 1);
  __syncthreads();
  if (t < 64){
    rb64[t] = h64[t] ? atomicAdd(&bcursor[bin*64 + t], h64[t]) : 0;
    h64[t] = 0;
  }
  __syncthreads();
  for (int e = lo + t; e < hi; e += 256){
    unsigned u = ebin[e];
    int bib = (u >> 24) & 63;
    int p = rb64[bib] + atomicAdd(&h64[bib], 1);
    ebuck[p] = u & 0xFFFFFFu;
  }
}

// ---------------- conversions / weight prep ----------------
__global__ void tobf16_kernel(const float* __restrict__ xf, __bf16* __restrict__ xb){
  int i = (blockIdx.x*256 + threadIdx.x)*8;
  if (i < NN*64){
    f32x4 a = *(const f32x4*)(xf + i);
    f32x4 b = *(const f32x4*)(xf + i + 4);
    bf16x8 r;
    r[0]=(__bf16)a[0]; r[1]=(__bf16)a[1]; r[2]=(__bf16)a[2]; r[3]=(__bf16)a[3];
    r[4]=(__bf16)b[0]; r[5]=(__bf16)b[1]; r[6]=(__bf16)b[2]; r[7]=(__bf16)b[3];
    *(bf16x8*)(xb + i) = r;
  }
}

// W1=[w|ws] (64 x 320), W2=[pw;tw] (128 x 128), bias1=b+bs, bias2=[pb|tb]
__global__ void prep_kernel(const float* __restrict__ w,  const float* __restrict__ b,
                            const float* __restrict__ ws, const float* __restrict__ bs,
                            const float* __restrict__ pw, const float* __restrict__ pb,
                            const float* __restrict__ tw, const float* __restrict__ tb,
                            __bf16* __restrict__ W1, __bf16* __restrict__ W2,
                            float* __restrict__ bias1, float* __restrict__ bias2){
  int i = blockIdx.x*256 + threadIdx.x;
  if (i < 64*320) {
    int n = i/320, k = i - n*320;
    float v = (k < 256) ? w[n*256+k] : ws[n*64 + (k-256)];
    W1[i] = (__bf16)v;
  }
  if (i < 128*128) {
    int n = i >> 7, k = i & 127;
    float v = (n < 64) ? pw[n*128+k] : tw[(n-64)*128+k];
    W2[i] = (__bf16)v;
  }
  if (i < 64)  bias1[i] = b[i] + bs[i];
  if (i < 128) bias2[i] = (i < 64) ? pb[i] : tb[i-64];
}

// ---------------- fused: local sort + gather-mean + GEMM1 + GEMM2 ----------------
// One block per bucket = 128 segments = 32 nodes. 256 threads (4 waves).
//   Phase S: edges staged in registers; LDS histogram; wave-0 shuffle scan; place.
//   Phase G: flattened segmented mean — group g walks its contiguous range of
//            8 segments 4-wide (4 gather loads in flight), boundary-flush to am.
//   Phase M: GEMM1 [32x320]@W1^T -> sigmoid -> h ; GEMM2 [h|prev]@W2^T -> highway.
#define AMP 264   // am pitch (bf16)
#define HSP 72    // hstage pitch

template<bool LAYER1>
__global__ __launch_bounds__(256)
void fused_kernel(const unsigned* __restrict__ ebuck, const int* __restrict__ boff,
                  const __bf16* __restrict__ inb,    // conv input: gather source + self rows
                  const __bf16* __restrict__ prevb,  // highway prev rows
                  const __bf16* __restrict__ W1,     // [64][320]
                  const __bf16* __restrict__ W2,     // [128][128]
                  const float* __restrict__ bias1,   // [64]
                  const float* __restrict__ bias2,   // [128]
                  __bf16* __restrict__ hb,           // layer1: conv out
                  __bf16* __restrict__ gb,           // layer1: highway out
                  float* __restrict__ outp)          // layer2: final fp32
{
  __shared__ int lcnt[128], lcur[128];
  __shared__ __align__(16) char u_mem[SSZ*4];   // 5120B: ssrc (S/G) ∪ hstage (M)
  __shared__ __bf16 am[32*AMP];                 // 16.9 KB means / A-operand [32][256]
  int*    ssrc   = (int*)u_mem;
  __bf16* hstage = (__bf16*)u_mem;              // 32*HSP*2 = 4608B <= 5120B

  const int b = blockIdx.x;
  const int t = threadIdx.x;
  const int e0 = boff[b], e1 = boff[b+1];

  // pre-zero am (empty segments must read as 0)
  for (int i = t; i < 32*AMP/2; i += 256) ((unsigned*)am)[i] = 0u;
  if (t < 128) lcnt[t] = 0;
  __syncthreads();

  // ---- Phase S: stage edges in regs, histogram, scan, place (sorted by seg) ----
  unsigned ev[8]; int nk = 0;
  #pragma unroll
  for (int k = 0; k < 8; ++k){
    int e = e0 + t + k*256;
    if (e < e1) ev[nk++] = ebuck[e];
  }
  for (int k = 0; k < nk; ++k)
    atomicAdd(&lcnt[(ev[k] >> 17) & 127], 1);
  __syncthreads();
  if (t < 64){                        // wave 0: shuffle-scan 128 counts (2/lane)
    int c0 = lcnt[2*t], c1 = lcnt[2*t+1];
    int s = c0 + c1;
    #pragma unroll
    for (int o = 1; o < 64; o <<= 1){
      int u = __shfl_up(s, o);
      if (t >= o) s += u;
    }
    lcur[2*t]   = s - c1 - c0;        // exclusive starts
    lcur[2*t+1] = s - c1;
  }
  __syncthreads();
  for (int k = 0; k < nk; ++k){
    int sl = (ev[k] >> 17) & 127;
    int p = atomicAdd(&lcur[sl], 1);
    if (p < SSZ) ssrc[p] = (int)ev[k];    // keep lseg bits for Phase G
  }
  __syncthreads();
  // now lcur[sl] = end offset, lcnt[sl] = count

  // ---- Phase G: flattened segmented mean, 4 loads in flight ----
  {
    const int fl = t & 15;
    const int g8 = (t >> 4) * 8;          // first segment of this 16-lane group
    int lo  = lcur[g8] - lcnt[g8];
    int hi  = lcur[g8 + 7];
    int cur = g8;
    f32x4 a = {0.f,0.f,0.f,0.f};
    for (int i = lo; i < hi; i += 4){
      int n = hi - i; if (n > 4) n = 4;
      unsigned e[4]; bf16x4 v[4];
      e[0] = (unsigned)ssrc[i];
      e[1] = (1 < n) ? (unsigned)ssrc[i+1] : e[0];
      e[2] = (2 < n) ? (unsigned)ssrc[i+2] : e[0];
      e[3] = (3 < n) ? (unsigned)ssrc[i+3] : e[0];
      #pragma unroll
      for (int k = 0; k < 4; ++k)
        v[k] = *(const bf16x4*)(&inb[(size_t)(e[k] & 0x1FFFFu)*64 + fl*4]);
      #pragma unroll
      for (int k = 0; k < 4; ++k){
        if (k < n){
          int sl = (int)((e[k] >> 17) & 127);
          if (sl != cur){
            float iv = 1.0f / fmaxf((float)lcnt[cur], 1.0f);
            bf16x4 r;
            r[0]=(__bf16)(a[0]*iv); r[1]=(__bf16)(a[1]*iv);
            r[2]=(__bf16)(a[2]*iv); r[3]=(__bf16)(a[3]*iv);
            *(bf16x4*)(&am[(cur>>2)*AMP + (cur&3)*64 + fl*4]) = r;
            a = f32x4{0.f,0.f,0.f,0.f}; cur = sl;
          }
          a[0]+=(float)v[k][0]; a[1]+=(float)v[k][1];
          a[2]+=(float)v[k][2]; a[3]+=(float)v[k][3];
        }
      }
    }
    float iv = 1.0f / fmaxf((float)lcnt[cur], 1.0f);
    bf16x4 r;
    r[0]=(__bf16)(a[0]*iv); r[1]=(__bf16)(a[1]*iv);
    r[2]=(__bf16)(a[2]*iv); r[3]=(__bf16)(a[3]*iv);
    *(bf16x4*)(&am[(cur>>2)*AMP + (cur&3)*64 + fl*4]) = r;
  }
  __syncthreads();   // am ready; ssrc dead (hstage may reuse u_mem after this point)

  // ---- Phase M: MFMA ----
  const int lane = t & 63;
  const int wv   = t >> 6;
  const int mloc = lane & 15;
  const int kg   = lane >> 4;
  const int mt   = wv & 1;        // m-tile (16 rows)
  const int nh   = wv >> 1;       // column half
  const int arowL = mt*16 + mloc; // local A row 0..31
  const size_t nodeA = (size_t)(b*32 + arowL);

  f32x4 acc1[2] = {};             // GEMM1 n-tiles nh*2, nh*2+1
  #pragma unroll
  for (int kb = 0; kb < 256; kb += 32){
    bf16x8 af = *(const bf16x8*)(&am[arowL*AMP + kb + kg*8]);
    #pragma unroll
    for (int jj = 0; jj < 2; ++jj){
      int j = nh*2 + jj;
      bf16x8 bf = *(const bf16x8*)(&W1[(j*16 + mloc)*320 + kb + kg*8]);
      acc1[jj] = __builtin_amdgcn_mfma_f32_16x16x32_bf16(af, bf, acc1[jj], 0,0,0);
    }
  }
  #pragma unroll
  for (int kb = 0; kb < 64; kb += 32){     // self-loop K=256..320
    bf16x8 af = *(const bf16x8*)(&inb[nodeA*64 + kb + kg*8]);
    #pragma unroll
    for (int jj = 0; jj < 2; ++jj){
      int j = nh*2 + jj;
      bf16x8 bf = *(const bf16x8*)(&W1[(j*16 + mloc)*320 + 256 + kb + kg*8]);
      acc1[jj] = __builtin_amdgcn_mfma_f32_16x16x32_bf16(af, bf, acc1[jj], 0,0,0);
    }
  }

  // epilogue 1: h = sigmoid(acc + bias1)
  #pragma unroll
  for (int jj = 0; jj < 2; ++jj){
    int col = nh*32 + jj*16 + mloc;
    float b1 = bias1[col];
    #pragma unroll
    for (int r = 0; r < 4; ++r){
      float hv = sigmoidf_(acc1[jj][r] + b1);
      acc1[jj][r] = hv;
      int hrow = mt*16 + kg*4 + r;
      hstage[hrow*HSP + col] = (__bf16)hv;
      if (LAYER1) hb[(size_t)(b*32 + hrow)*64 + col] = (__bf16)hv;
    }
  }
  __syncthreads();

  f32x4 acc2[4] = {};   // q<2: pr tiles nh*2+q ; q>=2: g tiles 4+nh*2+(q-2)
  #pragma unroll
  for (int kb = 0; kb < 64; kb += 32){     // K 0..64: A = h from LDS
    bf16x8 af = *(const bf16x8*)(&hstage[arowL*HSP + kb + kg*8]);
    #pragma unroll
    for (int q = 0; q < 4; ++q){
      int j = (q < 2) ? (nh*2 + q) : (4 + nh*2 + (q-2));
      bf16x8 bf = *(const bf16x8*)(&W2[(j*16 + mloc)*128 + kb + kg*8]);
      acc2[q] = __builtin_amdgcn_mfma_f32_16x16x32_bf16(af, bf, acc2[q], 0,0,0);
    }
  }
  #pragma unroll
  for (int kb = 0; kb < 64; kb += 32){     // K 64..128: A = prev rows (global)
    bf16x8 af = *(const bf16x8*)(&prevb[nodeA*64 + kb + kg*8]);
    #pragma unroll
    for (int q = 0; q < 4; ++q){
      int j = (q < 2) ? (nh*2 + q) : (4 + nh*2 + (q-2));
      bf16x8 bf = *(const bf16x8*)(&W2[(j*16 + mloc)*128 + 64 + kb + kg*8]);
      acc2[q] = __builtin_amdgcn_mfma_f32_16x16x32_bf16(af, bf, acc2[q], 0,0,0);
    }
  }

  // epilogue 2: highway
  #pragma unroll
  for (int jj = 0; jj < 2; ++jj){
    int col = nh*32 + jj*16 + mloc;
    float bp = bias2[col];
    float bt = bias2[64 + col];
    #pragma unroll
    for (int r = 0; r < 4; ++r){
      float pr = fmaxf(acc2[jj][r] + bp, 0.0f);
      float g  = sigmoidf_(acc2[jj+2][r] + bt);
      float hv = acc1[jj][r];
      float ov = g*pr + (1.0f - g)*hv;
      size_t grow = (size_t)(b*32 + mt*16 + kg*4 + r);
      if (LAYER1) gb[grow*64 + col] = (__bf16)ov;
      else        outp[grow*64 + col] = ov;
    }
  }
}

extern "C" void kernel_launch(void* const* d_in, const int* in_sizes, int n_in,
                              void* d_out, int out_size, void* d_ws, size_t ws_size,
                              hipStream_t stream){
  const float* x    = (const float*)d_in[0];
  const int*   src  = (const int*)d_in[1];
  const int*   dst  = (const int*)d_in[2];
  const int*   rel  = (const int*)d_in[3];
  const float* c1w  = (const float*)d_in[4];
  const float* c1b  = (const float*)d_in[5];
  const float* c1ws = (const float*)d_in[6];
  const float* c1bs = (const float*)d_in[7];
  const float* h1pw = (const float*)d_in[8];
  const float* h1pb = (const float*)d_in[9];
  const float* h1tw = (const float*)d_in[10];
  const float* h1tb = (const float*)d_in[11];
  const float* c2w  = (const float*)d_in[12];
  const float* c2b  = (const float*)d_in[13];
  const float* c2ws = (const float*)d_in[14];
  const float* c2bs = (const float*)d_in[15];
  const float* h2pw = (const float*)d_in[16];
  const float* h2pb = (const float*)d_in[17];
  const float* h2tw = (const float*)d_in[18];
  const float* h2tb = (const float*)d_in[19];

  char* p = (char*)d_ws;
  __bf16* xb   = (__bf16*)p;  p += (size_t)NN*64*2;
  __bf16* h1b  = (__bf16*)p;  p += (size_t)NN*64*2;
  __bf16* g1b  = (__bf16*)p;  p += (size_t)NN*64*2;
  unsigned* ebuck = (unsigned*)p; p += (size_t)NE*4;
  unsigned* ebin  = (unsigned*)p; p += (size_t)NE*4;
  int* bcnt    = (int*)p;     p += 3200*4;   // memset covers bcnt+bincnt
  int* bincnt  = (int*)p;     p += 64*4;
  int* bincur  = (int*)p;     p += 64*4;
  int* boff    = (int*)p;     p += 3200*4;
  int* bcursor = (int*)p;     p += 3200*4;
  __bf16* W1a  = (__bf16*)p;  p += 64*320*2;
  __bf16* W2a  = (__bf16*)p;  p += 128*128*2;
  __bf16* W1b  = (__bf16*)p;  p += 64*320*2;
  __bf16* W2b  = (__bf16*)p;  p += 128*128*2;
  float* B1a   = (float*)p;   p += 64*4;
  float* B2a   = (float*)p;   p += 128*4;
  float* B1b   = (float*)p;   p += 64*4;
  float* B2b   = (float*)p;   p += 128*4;

  float* out = (float*)d_out;

  // two-pass bucketed counting sort of edges (shared by both layers)
  hipMemsetAsync(bcnt, 0, (3200+64)*4, stream);
  binhist_kernel<<<64, 256, 0, stream>>>(dst, rel, bincnt);
  binscan_kernel<<<1, 64, 0, stream>>>(bincnt, bincur);
  passA_kernel<<<(NE+8191)/8192, 256, 0, stream>>>(src, dst, rel, bincur, bcnt, ebin);
  bscan_kernel<<<1, 256, 0, stream>>>(bcnt, boff, bcursor);
  passB_kernel<<<NBIN*4, 256, 0, stream>>>(ebin, boff, bcursor, ebuck);

  tobf16_kernel<<<(NN*64/8 + 255)/256, 256, 0, stream>>>(x, xb);
  prep_kernel<<<80, 256, 0, stream>>>(c1w, c1b, c1ws, c1bs, h1pw, h1pb, h1tw, h1tb,
                                      W1a, W2a, B1a, B2a);
  prep_kernel<<<80, 256, 0, stream>>>(c2w, c2b, c2ws, c2bs, h2pw, h2pb, h2tw, h2tb,
                                      W1b, W2b, B1b, B2b);

  // layer 1: conv input x, highway prev = x
  fused_kernel<true><<<NBUK, 256, 0, stream>>>(ebuck, boff, xb, xb,
                                               W1a, W2a, B1a, B2a, h1b, g1b, nullptr);
  // layer 2: conv input g1, highway prev = h1
  fused_kernel<false><<<NBUK, 256, 0, stream>>>(ebuck, boff, g1b, h1b,
                                                W1b, W2b, B1b, B2b, nullptr, nullptr, out);
}

// Round 7
// 359.999 us; speedup vs baseline: 3.5207x; 1.0369x over previous
//
#include <hip/hip_runtime.h>

#define NN 100000            // nodes
#define NE 1200000           // edges
#define NRR 400000           // N*R segments
#define NBUK 3125            // buckets of 128 segs (= 32 nodes); 3125*128 == NRR
#define NBIN 98              // bins of 4096 segs (32 buckets): ceil(400000/4096)
#define SSZ 1280             // per-bucket edge capacity in LDS (mean 384)

typedef float f32x4 __attribute__((ext_vector_type(4)));
typedef __bf16 bf16x4 __attribute__((ext_vector_type(4)));
typedef __bf16 bf16x8 __attribute__((ext_vector_type(8)));

__device__ __forceinline__ float sigmoidf_(float x){ return 1.0f/(1.0f+__expf(-x)); }

// ---------------- bin histogram (98 bins of 4096 segs) ----------------
__global__ __launch_bounds__(256)
void binhist_kernel(const int* __restrict__ dst, const int* __restrict__ rel,
                    int* __restrict__ bincnt){
  __shared__ int h[NBIN];
  int t = threadIdx.x;
  if (t < NBIN) h[t] = 0;
  __syncthreads();
  for (int e = blockIdx.x*256 + t; e < NE; e += 64*256){
    int bin = (dst[e]*4 + rel[e]) >> 12;
    atomicAdd(&h[bin], 1);
  }
  __syncthreads();
  if (t < NBIN && h[t]) atomicAdd(&bincnt[t], h[t]);
}

// ---------------- tiny exclusive scan of 98 bins + sentinels ----------------
__global__ void binscan_kernel(const int* __restrict__ bincnt, int* __restrict__ binoff,
                               int* __restrict__ bincur, int* __restrict__ soff){
  if (threadIdx.x == 0){
    int s = 0;
    for (int i = 0; i < NBIN; ++i){ binoff[i] = s; bincur[i] = s; s += bincnt[i]; }
    binoff[NBIN] = NE;
    soff[NRR] = NE;
  }
}

// ---------------- pass A: sort edges into 98 bins ----------------
// Each block owns an 8192-edge chunk; reserves ONE run per bin (~84 entries,
// ~5 lines) so lines are (mostly) written by one block -> L2 merges writebacks.
// ebin entry = src | (seg_in_bin << 17), seg_in_bin = seg & 4095 (12 bits).
__global__ __launch_bounds__(256)
void passA_kernel(const int* __restrict__ src, const int* __restrict__ dst,
                  const int* __restrict__ rel, int* __restrict__ bincur,
                  unsigned* __restrict__ ebin){
  __shared__ int h[NBIN], runbase[NBIN];
  int t = threadIdx.x;
  if (t < NBIN) h[t] = 0;
  __syncthreads();
  int lo = blockIdx.x*8192, hi = min(lo + 8192, NE);
  for (int e = lo + t; e < hi; e += 256)
    atomicAdd(&h[(dst[e]*4 + rel[e]) >> 12], 1);
  __syncthreads();
  if (t < NBIN){
    runbase[t] = h[t] ? atomicAdd(&bincur[t], h[t]) : 0;
    h[t] = 0;
  }
  __syncthreads();
  for (int e = lo + t; e < hi; e += 256){
    int seg = dst[e]*4 + rel[e];
    int bin = seg >> 12;
    int p = runbase[bin] + atomicAdd(&h[bin], 1);
    ebin[p] = (unsigned)src[e] | ((unsigned)(seg & 4095) << 17);
  }
}

// ---------------- pass B: per-bin segment-level counting sort ----------------
// One 1024-thread block per bin. 4096-entry LDS hist -> block scan -> writes
// global soff[] (absolute per-segment offsets) and segment-sorted ebuck (src only).
// Entire bin output region (~49KB) written by this one block -> full-line WBs.
__global__ __launch_bounds__(1024)
void passB_kernel(const unsigned* __restrict__ ebin, const int* __restrict__ binoff,
                  int* __restrict__ soff, unsigned* __restrict__ ebuck){
  __shared__ int st[4096];          // hist -> absolute starts -> cursors
  __shared__ int wsum[16], wbase[16];
  const int bin = blockIdx.x;
  const int t = threadIdx.x;
  const int base = binoff[bin], end = binoff[bin+1];
  #pragma unroll
  for (int i = 0; i < 4; ++i) st[t*4 + i] = 0;
  __syncthreads();
  for (int e = base + t; e < end; e += 1024)
    atomicAdd(&st[(ebin[e] >> 17) & 4095], 1);
  __syncthreads();
  // block-wide exclusive scan of 4096 counts (4 contiguous per thread)
  int h0 = st[t*4], h1 = st[t*4+1], h2 = st[t*4+2], h3 = st[t*4+3];
  int lsum = h0 + h1 + h2 + h3;
  int lane = t & 63, wv = t >> 6;
  int inc = lsum;
  #pragma unroll
  for (int o = 1; o < 64; o <<= 1){ int u = __shfl_up(inc, o); if (lane >= o) inc += u; }
  if (lane == 63) wsum[wv] = inc;
  __syncthreads();
  if (t == 0){ int s = 0; for (int i = 0; i < 16; ++i){ wbase[i] = s; s += wsum[i]; } }
  __syncthreads();
  int ex = base + wbase[wv] + (inc - lsum);   // absolute start of this thread's 4 segs
  int s0 = ex, s1 = ex + h0, s2 = s1 + h1, s3 = s2 + h2;
  st[t*4] = s0; st[t*4+1] = s1; st[t*4+2] = s2; st[t*4+3] = s3;
  int sg = bin*4096 + t*4;
  if (sg   < NRR) soff[sg]   = s0;
  if (sg+1 < NRR) soff[sg+1] = s1;
  if (sg+2 < NRR) soff[sg+2] = s2;
  if (sg+3 < NRR) soff[sg+3] = s3;
  __syncthreads();
  for (int e = base + t; e < end; e += 1024){
    unsigned u = ebin[e];
    int p = atomicAdd(&st[(u >> 17) & 4095], 1);
    ebuck[p] = u & 0x1FFFFu;
  }
}

// ---------------- conversions / weight prep ----------------
__global__ void tobf16_kernel(const float* __restrict__ xf, __bf16* __restrict__ xb){
  int i = (blockIdx.x*256 + threadIdx.x)*8;
  if (i < NN*64){
    f32x4 a = *(const f32x4*)(xf + i);
    f32x4 b = *(const f32x4*)(xf + i + 4);
    bf16x8 r;
    r[0]=(__bf16)a[0]; r[1]=(__bf16)a[1]; r[2]=(__bf16)a[2]; r[3]=(__bf16)a[3];
    r[4]=(__bf16)b[0]; r[5]=(__bf16)b[1]; r[6]=(__bf16)b[2]; r[7]=(__bf16)b[3];
    *(bf16x8*)(xb + i) = r;
  }
}

// W1=[w|ws] (64 x 320), W2=[pw;tw] (128 x 128), bias1=b+bs, bias2=[pb|tb]
__global__ void prep_kernel(const float* __restrict__ w,  const float* __restrict__ b,
                            const float* __restrict__ ws, const float* __restrict__ bs,
                            const float* __restrict__ pw, const float* __restrict__ pb,
                            const float* __restrict__ tw, const float* __restrict__ tb,
                            __bf16* __restrict__ W1, __bf16* __restrict__ W2,
                            float* __restrict__ bias1, float* __restrict__ bias2){
  int i = blockIdx.x*256 + threadIdx.x;
  if (i < 64*320) {
    int n = i/320, k = i - n*320;
    float v = (k < 256) ? w[n*256+k] : ws[n*64 + (k-256)];
    W1[i] = (__bf16)v;
  }
  if (i < 128*128) {
    int n = i >> 7, k = i & 127;
    float v = (n < 64) ? pw[n*128+k] : tw[(n-64)*128+k];
    W2[i] = (__bf16)v;
  }
  if (i < 64)  bias1[i] = b[i] + bs[i];
  if (i < 128) bias2[i] = (i < 64) ? pb[i] : tb[i-64];
}

// ---------------- fused: gather-mean + GEMM1 + GEMM2 ----------------
// One block per bucket = 128 segments = 32 nodes. 256 threads (4 waves).
// Input is already segment-sorted; soff gives per-segment ranges.
//   Phase G: 8-lane groups x bf16x8, 4 segs/group, plain accumulate loops.
//   Phase M: GEMM1 [32x320]@W1^T -> sigmoid -> h ; GEMM2 [h|prev]@W2^T -> highway.
#define AMP 264   // am pitch (bf16)
#define HSP 72    // hstage pitch

template<bool LAYER1>
__global__ __launch_bounds__(256)
void fused_kernel(const unsigned* __restrict__ ebuck, const int* __restrict__ soff,
                  const __bf16* __restrict__ inb,    // conv input: gather source + self rows
                  const __bf16* __restrict__ prevb,  // highway prev rows
                  const __bf16* __restrict__ W1,     // [64][320]
                  const __bf16* __restrict__ W2,     // [128][128]
                  const float* __restrict__ bias1,   // [64]
                  const float* __restrict__ bias2,   // [128]
                  __bf16* __restrict__ hb,           // layer1: conv out
                  __bf16* __restrict__ gb,           // layer1: highway out
                  float* __restrict__ outp)          // layer2: final fp32
{
  __shared__ int sof[129];
  __shared__ __align__(16) char u_mem[SSZ*4];   // ssrc (G) ∪ hstage (M)
  __shared__ __bf16 am[32*AMP];                 // 16.9 KB means / A-operand [32][256]
  int*    ssrc   = (int*)u_mem;
  __bf16* hstage = (__bf16*)u_mem;              // 32*HSP*2 = 4608B <= 5120B

  const int b = blockIdx.x;
  const int t = threadIdx.x;

  if (t < 129) sof[t] = soff[b*128 + t];        // soff[NRR]=NE sentinel covers b=NBUK-1
  __syncthreads();
  const int e0 = sof[0], e1 = sof[128];
  for (int e = e0 + t; e < e1; e += 256){
    int o = e - e0;
    if (o < SSZ) ssrc[o] = (int)ebuck[e];
  }
  __syncthreads();

  // ---- Phase G: 32 groups of 8 lanes; group g owns segs [g*4, g*4+4) ----
  {
    const int fl = t & 7;           // feature octet [fl*8, fl*8+8)
    const int g  = t >> 3;
    #pragma unroll
    for (int q = 0; q < 4; ++q){
      int sl = g*4 + q;
      int o0 = sof[sl] - e0;
      int c  = sof[sl+1] - sof[sl];
      f32x4 a0 = {0.f,0.f,0.f,0.f}, a1 = {0.f,0.f,0.f,0.f};
      for (int i = 0; i < c; ++i){
        int idx = o0 + i; if (idx >= SSZ) idx = SSZ-1;
        int s = ssrc[idx];
        bf16x8 v = *(const bf16x8*)(&inb[(size_t)s*64 + fl*8]);
        a0[0]+=(float)v[0]; a0[1]+=(float)v[1]; a0[2]+=(float)v[2]; a0[3]+=(float)v[3];
        a1[0]+=(float)v[4]; a1[1]+=(float)v[5]; a1[2]+=(float)v[6]; a1[3]+=(float)v[7];
      }
      float inv = 1.0f / fmaxf((float)c, 1.0f);
      bf16x8 r;
      r[0]=(__bf16)(a0[0]*inv); r[1]=(__bf16)(a0[1]*inv);
      r[2]=(__bf16)(a0[2]*inv); r[3]=(__bf16)(a0[3]*inv);
      r[4]=(__bf16)(a1[0]*inv); r[5]=(__bf16)(a1[1]*inv);
      r[6]=(__bf16)(a1[2]*inv); r[7]=(__bf16)(a1[3]*inv);
      // seg sl -> node row sl>>2, K offset (sl&3)*64
      *(bf16x8*)(&am[(sl>>2)*AMP + (sl&3)*64 + fl*8]) = r;
    }
  }
  __syncthreads();   // am ready; ssrc dead (hstage may reuse u_mem)

  // ---- Phase M: MFMA ----
  const int lane = t & 63;
  const int wv   = t >> 6;
  const int mloc = lane & 15;
  const int kg   = lane >> 4;
  const int mt   = wv & 1;        // m-tile (16 rows)
  const int nh   = wv >> 1;       // column half
  const int arowL = mt*16 + mloc; // local A row 0..31
  const size_t nodeA = (size_t)(b*32 + arowL);

  f32x4 acc1[2] = {};             // GEMM1 n-tiles nh*2, nh*2+1
  #pragma unroll
  for (int kb = 0; kb < 256; kb += 32){
    bf16x8 af = *(const bf16x8*)(&am[arowL*AMP + kb + kg*8]);
    #pragma unroll
    for (int jj = 0; jj < 2; ++jj){
      int j = nh*2 + jj;
      bf16x8 bf = *(const bf16x8*)(&W1[(j*16 + mloc)*320 + kb + kg*8]);
      acc1[jj] = __builtin_amdgcn_mfma_f32_16x16x32_bf16(af, bf, acc1[jj], 0,0,0);
    }
  }
  #pragma unroll
  for (int kb = 0; kb < 64; kb += 32){     // self-loop K=256..320
    bf16x8 af = *(const bf16x8*)(&inb[nodeA*64 + kb + kg*8]);
    #pragma unroll
    for (int jj = 0; jj < 2; ++jj){
      int j = nh*2 + jj;
      bf16x8 bf = *(const bf16x8*)(&W1[(j*16 + mloc)*320 + 256 + kb + kg*8]);
      acc1[jj] = __builtin_amdgcn_mfma_f32_16x16x32_bf16(af, bf, acc1[jj], 0,0,0);
    }
  }

  // epilogue 1: h = sigmoid(acc + bias1)
  #pragma unroll
  for (int jj = 0; jj < 2; ++jj){
    int col = nh*32 + jj*16 + mloc;
    float b1 = bias1[col];
    #pragma unroll
    for (int r = 0; r < 4; ++r){
      float hv = sigmoidf_(acc1[jj][r] + b1);
      acc1[jj][r] = hv;
      int hrow = mt*16 + kg*4 + r;
      hstage[hrow*HSP + col] = (__bf16)hv;
      if (LAYER1) hb[(size_t)(b*32 + hrow)*64 + col] = (__bf16)hv;
    }
  }
  __syncthreads();

  f32x4 acc2[4] = {};   // q<2: pr tiles nh*2+q ; q>=2: g tiles 4+nh*2+(q-2)
  #pragma unroll
  for (int kb = 0; kb < 64; kb += 32){     // K 0..64: A = h from LDS
    bf16x8 af = *(const bf16x8*)(&hstage[arowL*HSP + kb + kg*8]);
    #pragma unroll
    for (int q = 0; q < 4; ++q){
      int j = (q < 2) ? (nh*2 + q) : (4 + nh*2 + (q-2));
      bf16x8 bf = *(const bf16x8*)(&W2[(j*16 + mloc)*128 + kb + kg*8]);
      acc2[q] = __builtin_amdgcn_mfma_f32_16x16x32_bf16(af, bf, acc2[q], 0,0,0);
    }
  }
  #pragma unroll
  for (int kb = 0; kb < 64; kb += 32){     // K 64..128: A = prev rows (global)
    bf16x8 af = *(const bf16x8*)(&prevb[nodeA*64 + kb + kg*8]);
    #pragma unroll
    for (int q = 0; q < 4; ++q){
      int j = (q < 2) ? (nh*2 + q) : (4 + nh*2 + (q-2));
      bf16x8 bf = *(const bf16x8*)(&W2[(j*16 + mloc)*128 + 64 + kb + kg*8]);
      acc2[q] = __builtin_amdgcn_mfma_f32_16x16x32_bf16(af, bf, acc2[q], 0,0,0);
    }
  }

  // epilogue 2: highway
  #pragma unroll
  for (int jj = 0; jj < 2; ++jj){
    int col = nh*32 + jj*16 + mloc;
    float bp = bias2[col];
    float bt = bias2[64 + col];
    #pragma unroll
    for (int r = 0; r < 4; ++r){
      float pr = fmaxf(acc2[jj][r] + bp, 0.0f);
      float g  = sigmoidf_(acc2[jj+2][r] + bt);
      float hv = acc1[jj][r];
      float ov = g*pr + (1.0f - g)*hv;
      size_t grow = (size_t)(b*32 + mt*16 + kg*4 + r);
      if (LAYER1) gb[grow*64 + col] = (__bf16)ov;
      else        outp[grow*64 + col] = ov;
    }
  }
}

extern "C" void kernel_launch(void* const* d_in, const int* in_sizes, int n_in,
                              void* d_out, int out_size, void* d_ws, size_t ws_size,
                              hipStream_t stream){
  const float* x    = (const float*)d_in[0];
  const int*   src  = (const int*)d_in[1];
  const int*   dst  = (const int*)d_in[2];
  const int*   rel  = (const int*)d_in[3];
  const float* c1w  = (const float*)d_in[4];
  const float* c1b  = (const float*)d_in[5];
  const float* c1ws = (const float*)d_in[6];
  const float* c1bs = (const float*)d_in[7];
  const float* h1pw = (const float*)d_in[8];
  const float* h1pb = (const float*)d_in[9];
  const float* h1tw = (const float*)d_in[10];
  const float* h1tb = (const float*)d_in[11];
  const float* c2w  = (const float*)d_in[12];
  const float* c2b  = (const float*)d_in[13];
  const float* c2ws = (const float*)d_in[14];
  const float* c2bs = (const float*)d_in[15];
  const float* h2pw = (const float*)d_in[16];
  const float* h2pb = (const float*)d_in[17];
  const float* h2tw = (const float*)d_in[18];
  const float* h2tb = (const float*)d_in[19];

  char* p = (char*)d_ws;
  __bf16* xb   = (__bf16*)p;  p += (size_t)NN*64*2;
  __bf16* h1b  = (__bf16*)p;  p += (size_t)NN*64*2;
  __bf16* g1b  = (__bf16*)p;  p += (size_t)NN*64*2;
  unsigned* ebuck = (unsigned*)p; p += (size_t)NE*4;
  unsigned* ebin  = (unsigned*)p; p += (size_t)NE*4;
  int* soff    = (int*)p;     p += (size_t)(NRR+8)*4;
  int* bincnt  = (int*)p;     p += 128*4;
  int* binoff  = (int*)p;     p += 128*4;
  int* bincur  = (int*)p;     p += 128*4;
  __bf16* W1a  = (__bf16*)p;  p += 64*320*2;
  __bf16* W2a  = (__bf16*)p;  p += 128*128*2;
  __bf16* W1b  = (__bf16*)p;  p += 64*320*2;
  __bf16* W2b  = (__bf16*)p;  p += 128*128*2;
  float* B1a   = (float*)p;   p += 64*4;
  float* B2a   = (float*)p;   p += 128*4;
  float* B1b   = (float*)p;   p += 64*4;
  float* B2b   = (float*)p;   p += 128*4;

  float* out = (float*)d_out;

  // segment-level counting sort of edges (shared by both layers)
  hipMemsetAsync(bincnt, 0, 128*4, stream);
  binhist_kernel<<<64, 256, 0, stream>>>(dst, rel, bincnt);
  binscan_kernel<<<1, 64, 0, stream>>>(bincnt, binoff, bincur, soff);
  passA_kernel<<<(NE+8191)/8192, 256, 0, stream>>>(src, dst, rel, bincur, ebin);
  passB_kernel<<<NBIN, 1024, 0, stream>>>(ebin, binoff, soff, ebuck);

  tobf16_kernel<<<(NN*64/8 + 255)/256, 256, 0, stream>>>(x, xb);
  prep_kernel<<<80, 256, 0, stream>>>(c1w, c1b, c1ws, c1bs, h1pw, h1pb, h1tw, h1tb,
                                      W1a, W2a, B1a, B2a);
  prep_kernel<<<80, 256, 0, stream>>>(c2w, c2b, c2ws, c2bs, h2pw, h2pb, h2tw, h2tb,
                                      W1b, W2b, B1b, B2b);

  // layer 1: conv input x, highway prev = x
  fused_kernel<true><<<NBUK, 256, 0, stream>>>(ebuck, soff, xb, xb,
                                               W1a, W2a, B1a, B2a, h1b, g1b, nullptr);
  // layer 2: conv input g1, highway prev = h1
  fused_kernel<false><<<NBUK, 256, 0, stream>>>(ebuck, soff, g1b, h1b,
                                                W1b, W2b, B1b, B2b, nullptr, nullptr, out);
}

// Round 8
// 353.912 us; speedup vs baseline: 3.5813x; 1.0172x over previous
//
#include <hip/hip_runtime.h>

#define NN 100000            // nodes
#define NE 1200000           // edges
#define NRR 400000           // N*R segments
#define NBIN 98              // bins of 4096 segs: ceil(400000/4096)
#define SSZ2 384             // per-gather-block edge capacity (mean 96, max ~160)

typedef float f32x4 __attribute__((ext_vector_type(4)));
typedef __bf16 bf16x4 __attribute__((ext_vector_type(4)));
typedef __bf16 bf16x8 __attribute__((ext_vector_type(8)));

__device__ __forceinline__ float sigmoidf_(float x){ return 1.0f/(1.0f+__expf(-x)); }

// ---------------- bin histogram (98 bins of 4096 segs) ----------------
__global__ __launch_bounds__(256)
void binhist_kernel(const int* __restrict__ dst, const int* __restrict__ rel,
                    int* __restrict__ bincnt){
  __shared__ int h[NBIN];
  int t = threadIdx.x;
  if (t < NBIN) h[t] = 0;
  __syncthreads();
  for (int e = blockIdx.x*256 + t; e < NE; e += 64*256){
    int bin = (dst[e]*4 + rel[e]) >> 12;
    atomicAdd(&h[bin], 1);
  }
  __syncthreads();
  if (t < NBIN && h[t]) atomicAdd(&bincnt[t], h[t]);
}

// ---------------- tiny exclusive scan of 98 bins + sentinels ----------------
__global__ void binscan_kernel(const int* __restrict__ bincnt, int* __restrict__ binoff,
                               int* __restrict__ bincur, int* __restrict__ soff){
  if (threadIdx.x == 0){
    int s = 0;
    for (int i = 0; i < NBIN; ++i){ binoff[i] = s; bincur[i] = s; s += bincnt[i]; }
    binoff[NBIN] = NE;
    soff[NRR] = NE;
  }
}

// ---------------- pass A: sort edges into 98 bins ----------------
// ebin entry = src | (seg_in_bin << 17), seg_in_bin = seg & 4095 (12 bits).
__global__ __launch_bounds__(256)
void passA_kernel(const int* __restrict__ src, const int* __restrict__ dst,
                  const int* __restrict__ rel, int* __restrict__ bincur,
                  unsigned* __restrict__ ebin){
  __shared__ int h[NBIN], runbase[NBIN];
  int t = threadIdx.x;
  if (t < NBIN) h[t] = 0;
  __syncthreads();
  int lo = blockIdx.x*8192, hi = min(lo + 8192, NE);
  for (int e = lo + t; e < hi; e += 256)
    atomicAdd(&h[(dst[e]*4 + rel[e]) >> 12], 1);
  __syncthreads();
  if (t < NBIN){
    runbase[t] = h[t] ? atomicAdd(&bincur[t], h[t]) : 0;
    h[t] = 0;
  }
  __syncthreads();
  for (int e = lo + t; e < hi; e += 256){
    int seg = dst[e]*4 + rel[e];
    int bin = seg >> 12;
    int p = runbase[bin] + atomicAdd(&h[bin], 1);
    ebin[p] = (unsigned)src[e] | ((unsigned)(seg & 4095) << 17);
  }
}

// ---------------- pass B: per-bin segment-level counting sort ----------------
__global__ __launch_bounds__(1024)
void passB_kernel(const unsigned* __restrict__ ebin, const int* __restrict__ binoff,
                  int* __restrict__ soff, unsigned* __restrict__ ebuck){
  __shared__ int st[4096];          // hist -> absolute starts -> cursors
  __shared__ int wsum[16], wbase[16];
  const int bin = blockIdx.x;
  const int t = threadIdx.x;
  const int base = binoff[bin], end = binoff[bin+1];
  #pragma unroll
  for (int i = 0; i < 4; ++i) st[t*4 + i] = 0;
  __syncthreads();
  for (int e = base + t; e < end; e += 1024)
    atomicAdd(&st[(ebin[e] >> 17) & 4095], 1);
  __syncthreads();
  int h0 = st[t*4], h1 = st[t*4+1], h2 = st[t*4+2], h3 = st[t*4+3];
  int lsum = h0 + h1 + h2 + h3;
  int lane = t & 63, wv = t >> 6;
  int inc = lsum;
  #pragma unroll
  for (int o = 1; o < 64; o <<= 1){ int u = __shfl_up(inc, o); if (lane >= o) inc += u; }
  if (lane == 63) wsum[wv] = inc;
  __syncthreads();
  if (t == 0){ int s = 0; for (int i = 0; i < 16; ++i){ wbase[i] = s; s += wsum[i]; } }
  __syncthreads();
  int ex = base + wbase[wv] + (inc - lsum);
  int s0 = ex, s1 = ex + h0, s2 = s1 + h1, s3 = s2 + h2;
  st[t*4] = s0; st[t*4+1] = s1; st[t*4+2] = s2; st[t*4+3] = s3;
  int sg = bin*4096 + t*4;
  if (sg   < NRR) soff[sg]   = s0;
  if (sg+1 < NRR) soff[sg+1] = s1;
  if (sg+2 < NRR) soff[sg+2] = s2;
  if (sg+3 < NRR) soff[sg+3] = s3;
  __syncthreads();
  for (int e = base + t; e < end; e += 1024){
    unsigned u = ebin[e];
    int p = atomicAdd(&st[(u >> 17) & 4095], 1);
    ebuck[p] = u & 0x1FFFFu;
  }
}

// ---------------- conversions / weight prep ----------------
__global__ void tobf16_kernel(const float* __restrict__ xf, __bf16* __restrict__ xb){
  int i = (blockIdx.x*256 + threadIdx.x)*8;
  if (i < NN*64){
    f32x4 a = *(const f32x4*)(xf + i);
    f32x4 b = *(const f32x4*)(xf + i + 4);
    bf16x8 r;
    r[0]=(__bf16)a[0]; r[1]=(__bf16)a[1]; r[2]=(__bf16)a[2]; r[3]=(__bf16)a[3];
    r[4]=(__bf16)b[0]; r[5]=(__bf16)b[1]; r[6]=(__bf16)b[2]; r[7]=(__bf16)b[3];
    *(bf16x8*)(xb + i) = r;
  }
}

// W1=[w|ws] (64 x 320), W2=[pw;tw] (128 x 128), bias1=b+bs, bias2=[pb|tb]
__global__ void prep_kernel(const float* __restrict__ w,  const float* __restrict__ b,
                            const float* __restrict__ ws, const float* __restrict__ bs,
                            const float* __restrict__ pw, const float* __restrict__ pb,
                            const float* __restrict__ tw, const float* __restrict__ tb,
                            __bf16* __restrict__ W1, __bf16* __restrict__ W2,
                            float* __restrict__ bias1, float* __restrict__ bias2){
  int i = blockIdx.x*256 + threadIdx.x;
  if (i < 64*320) {
    int n = i/320, k = i - n*320;
    float v = (k < 256) ? w[n*256+k] : ws[n*64 + (k-256)];
    W1[i] = (__bf16)v;
  }
  if (i < 128*128) {
    int n = i >> 7, k = i & 127;
    float v = (n < 64) ? pw[n*128+k] : tw[(n-64)*128+k];
    W2[i] = (__bf16)v;
  }
  if (i < 64)  bias1[i] = b[i] + bs[i];
  if (i < 128) bias2[i] = (i < 64) ? pb[i] : tb[i-64];
}

// ---------------- standalone gather-mean: max TLP for latency hiding ----------------
// 1 segment per 8-lane group, 32 segs/block, 12500 blocks. Tiny LDS -> 8 blocks/CU,
// ~256 groups/CU each a live gather stream (2-wide ILP) -> latency-hidden.
__global__ __launch_bounds__(256)
void gather_kernel(const unsigned* __restrict__ ebuck, const int* __restrict__ soff,
                   const __bf16* __restrict__ inb, __bf16* __restrict__ segb){
  __shared__ int sof[33];
  __shared__ int ssrc[SSZ2];
  const int b = blockIdx.x;
  const int t = threadIdx.x;
  if (t < 33) sof[t] = soff[b*32 + t];     // soff[NRR]=NE sentinel covers last block
  __syncthreads();
  const int e0 = sof[0], e1 = sof[32];
  for (int e = e0 + t; e < e1; e += 256){
    int o = e - e0;
    if (o < SSZ2) ssrc[o] = (int)ebuck[e];
  }
  __syncthreads();

  const int fl = t & 7;            // feature octet [fl*8, fl*8+8)
  const int g  = t >> 3;           // segment 0..31
  int o0 = sof[g] - e0;
  int c  = sof[g+1] - sof[g];
  if (o0 + c > SSZ2) c = max(0, SSZ2 - o0);   // defensive (never fires in practice)

  f32x4 a0 = {0.f,0.f,0.f,0.f}, a1 = {0.f,0.f,0.f,0.f};
  f32x4 b0 = {0.f,0.f,0.f,0.f}, b1 = {0.f,0.f,0.f,0.f};
  int i = 0;
  for (; i + 2 <= c; i += 2){
    int s0 = ssrc[o0+i], s1 = ssrc[o0+i+1];
    bf16x8 v0 = *(const bf16x8*)(&inb[(size_t)s0*64 + fl*8]);
    bf16x8 v1 = *(const bf16x8*)(&inb[(size_t)s1*64 + fl*8]);
    a0[0]+=(float)v0[0]; a0[1]+=(float)v0[1]; a0[2]+=(float)v0[2]; a0[3]+=(float)v0[3];
    a1[0]+=(float)v0[4]; a1[1]+=(float)v0[5]; a1[2]+=(float)v0[6]; a1[3]+=(float)v0[7];
    b0[0]+=(float)v1[0]; b0[1]+=(float)v1[1]; b0[2]+=(float)v1[2]; b0[3]+=(float)v1[3];
    b1[0]+=(float)v1[4]; b1[1]+=(float)v1[5]; b1[2]+=(float)v1[6]; b1[3]+=(float)v1[7];
  }
  if (i < c){
    int s0 = ssrc[o0+i];
    bf16x8 v0 = *(const bf16x8*)(&inb[(size_t)s0*64 + fl*8]);
    a0[0]+=(float)v0[0]; a0[1]+=(float)v0[1]; a0[2]+=(float)v0[2]; a0[3]+=(float)v0[3];
    a1[0]+=(float)v0[4]; a1[1]+=(float)v0[5]; a1[2]+=(float)v0[6]; a1[3]+=(float)v0[7];
  }
  float inv = 1.0f / fmaxf((float)c, 1.0f);
  bf16x8 r;
  r[0]=(__bf16)((a0[0]+b0[0])*inv); r[1]=(__bf16)((a0[1]+b0[1])*inv);
  r[2]=(__bf16)((a0[2]+b0[2])*inv); r[3]=(__bf16)((a0[3]+b0[3])*inv);
  r[4]=(__bf16)((a1[0]+b1[0])*inv); r[5]=(__bf16)((a1[1]+b1[1])*inv);
  r[6]=(__bf16)((a1[2]+b1[2])*inv); r[7]=(__bf16)((a1[3]+b1[3])*inv);
  *(bf16x8*)(&segb[(size_t)(b*32 + g)*64 + fl*8]) = r;   // empty segs write 0
}

// ---------------- dense + highway (round-2 structure, passed) ----------------
// Block = 128 nodes (two 64-row halves), 4 waves, 16x16x32 bf16 MFMA.
#define W2P 136   // LDS pitch (bf16) for W2
#define HSP 72    // LDS pitch (bf16) for h staging

template<bool LAYER1>
__global__ __launch_bounds__(256)
void dense_kernel(const __bf16* __restrict__ segb,  // [N*R,64] bf16 means (seg-ordered)
                  const __bf16* __restrict__ xinb,  // [N,64] conv self input
                  const __bf16* __restrict__ prevb, // [N,64] highway prev
                  const __bf16* __restrict__ W1,    // [64][320]
                  const __bf16* __restrict__ W2,    // [128][128]
                  const float* __restrict__ bias1,  // [64]
                  const float* __restrict__ bias2,  // [128]
                  __bf16* __restrict__ hb,          // layer1: conv out (bf16)
                  __bf16* __restrict__ gb,          // layer1: highway out (bf16)
                  float* __restrict__ outp)         // layer2: final fp32
{
  __shared__ __bf16 w2s[128*W2P];
  __shared__ __bf16 hs[128*HSP];

  const int tid = threadIdx.x;
  #pragma unroll
  for (int i = 0; i < 8; ++i) {
    int idx = i*2048 + tid*8;
    int n = idx >> 7, k = idx & 127;
    *(bf16x8*)(&w2s[n*W2P + k]) = *(const bf16x8*)(&W2[idx]);
  }
  __syncthreads();

  const int lane = tid & 63;
  const int wv   = tid >> 6;
  const int mloc = lane & 15;   // A-row / B-col within 16-tile
  const int kg   = lane >> 4;   // k-group
  const int base = blockIdx.x * 128;

  int arow[2];
  arow[0] = min(base      + wv*16 + mloc, NN-1);
  arow[1] = min(base + 64 + wv*16 + mloc, NN-1);

  f32x4 acc1[2][4] = {};

  // GEMM1 part 1: K = 0..256 from segb (upd)
  #pragma unroll
  for (int kb = 0; kb < 256; kb += 32) {
    bf16x8 bf[4];
    #pragma unroll
    for (int j = 0; j < 4; ++j)
      bf[j] = *(const bf16x8*)(&W1[(j*16 + mloc)*320 + kb + kg*8]);
    #pragma unroll
    for (int h = 0; h < 2; ++h) {
      bf16x8 af = *(const bf16x8*)(&segb[(size_t)arow[h]*256 + kb + kg*8]);
      #pragma unroll
      for (int j = 0; j < 4; ++j)
        acc1[h][j] = __builtin_amdgcn_mfma_f32_16x16x32_bf16(af, bf[j], acc1[h][j], 0,0,0);
    }
  }
  // GEMM1 part 2: K = 256..320 from xinb (self loop)
  #pragma unroll
  for (int kb = 0; kb < 64; kb += 32) {
    bf16x8 bf[4];
    #pragma unroll
    for (int j = 0; j < 4; ++j)
      bf[j] = *(const bf16x8*)(&W1[(j*16 + mloc)*320 + 256 + kb + kg*8]);
    #pragma unroll
    for (int h = 0; h < 2; ++h) {
      bf16x8 af = *(const bf16x8*)(&xinb[(size_t)arow[h]*64 + kb + kg*8]);
      #pragma unroll
      for (int j = 0; j < 4; ++j)
        acc1[h][j] = __builtin_amdgcn_mfma_f32_16x16x32_bf16(af, bf[j], acc1[h][j], 0,0,0);
    }
  }

  // epilogue 1: h = sigmoid(acc + bias1); stage bf16 in LDS (wave-private rows)
  #pragma unroll
  for (int h = 0; h < 2; ++h) {
    #pragma unroll
    for (int j = 0; j < 4; ++j) {
      int col = j*16 + mloc;
      float b1 = bias1[col];
      #pragma unroll
      for (int r = 0; r < 4; ++r) {
        float hv = sigmoidf_(acc1[h][j][r] + b1);
        acc1[h][j][r] = hv;
        int trow = h*64 + wv*16 + kg*4 + r;
        hs[trow*HSP + col] = (__bf16)hv;
        if (LAYER1) {
          int grow = base + trow;
          if (grow < NN) hb[(size_t)grow*64 + col] = (__bf16)hv;
        }
      }
    }
  }

  f32x4 acc2[2][8] = {};
  // GEMM2 part 1: K = 0..64 -> c = h (from LDS)
  #pragma unroll
  for (int kb = 0; kb < 64; kb += 32) {
    bf16x8 af[2];
    #pragma unroll
    for (int h = 0; h < 2; ++h) {
      int trow = h*64 + wv*16 + mloc;
      af[h] = *(const bf16x8*)(&hs[trow*HSP + kb + kg*8]);
    }
    #pragma unroll
    for (int j = 0; j < 8; ++j) {
      bf16x8 bf = *(const bf16x8*)(&w2s[(j*16 + mloc)*W2P + kb + kg*8]);
      #pragma unroll
      for (int h = 0; h < 2; ++h)
        acc2[h][j] = __builtin_amdgcn_mfma_f32_16x16x32_bf16(af[h], bf, acc2[h][j], 0,0,0);
    }
  }
  // GEMM2 part 2: K = 64..128 -> c = prev (global bf16)
  #pragma unroll
  for (int kb = 0; kb < 64; kb += 32) {
    bf16x8 af[2];
    #pragma unroll
    for (int h = 0; h < 2; ++h)
      af[h] = *(const bf16x8*)(&prevb[(size_t)arow[h]*64 + kb + kg*8]);
    #pragma unroll
    for (int j = 0; j < 8; ++j) {
      bf16x8 bf = *(const bf16x8*)(&w2s[(j*16 + mloc)*W2P + 64 + kb + kg*8]);
      #pragma unroll
      for (int h = 0; h < 2; ++h)
        acc2[h][j] = __builtin_amdgcn_mfma_f32_16x16x32_bf16(af[h], bf, acc2[h][j], 0,0,0);
    }
  }

  // epilogue 2: pr = relu(.+pb), g = sigmoid(.+tb), out = g*pr + (1-g)*h
  #pragma unroll
  for (int h = 0; h < 2; ++h) {
    #pragma unroll
    for (int j = 0; j < 4; ++j) {
      int col = j*16 + mloc;
      float bp = bias2[col];
      float bt = bias2[64 + col];
      #pragma unroll
      for (int r = 0; r < 4; ++r) {
        float pr = fmaxf(acc2[h][j][r] + bp, 0.0f);
        float g  = sigmoidf_(acc2[h][j+4][r] + bt);
        float hv = acc1[h][j][r];
        float ov = g*pr + (1.0f - g)*hv;
        int grow = base + h*64 + wv*16 + kg*4 + r;
        if (grow < NN) {
          if (LAYER1) gb[(size_t)grow*64 + col] = (__bf16)ov;
          else        outp[(size_t)grow*64 + col] = ov;
        }
      }
    }
  }
}

extern "C" void kernel_launch(void* const* d_in, const int* in_sizes, int n_in,
                              void* d_out, int out_size, void* d_ws, size_t ws_size,
                              hipStream_t stream){
  const float* x    = (const float*)d_in[0];
  const int*   src  = (const int*)d_in[1];
  const int*   dst  = (const int*)d_in[2];
  const int*   rel  = (const int*)d_in[3];
  const float* c1w  = (const float*)d_in[4];
  const float* c1b  = (const float*)d_in[5];
  const float* c1ws = (const float*)d_in[6];
  const float* c1bs = (const float*)d_in[7];
  const float* h1pw = (const float*)d_in[8];
  const float* h1pb = (const float*)d_in[9];
  const float* h1tw = (const float*)d_in[10];
  const float* h1tb = (const float*)d_in[11];
  const float* c2w  = (const float*)d_in[12];
  const float* c2b  = (const float*)d_in[13];
  const float* c2ws = (const float*)d_in[14];
  const float* c2bs = (const float*)d_in[15];
  const float* h2pw = (const float*)d_in[16];
  const float* h2pb = (const float*)d_in[17];
  const float* h2tw = (const float*)d_in[18];
  const float* h2tb = (const float*)d_in[19];

  char* p = (char*)d_ws;
  __bf16* segb = (__bf16*)p;  p += (size_t)NRR*64*2;
  __bf16* xb   = (__bf16*)p;  p += (size_t)NN*64*2;
  __bf16* h1b  = (__bf16*)p;  p += (size_t)NN*64*2;
  __bf16* g1b  = (__bf16*)p;  p += (size_t)NN*64*2;
  unsigned* ebuck = (unsigned*)p; p += (size_t)NE*4;
  unsigned* ebin  = (unsigned*)p; p += (size_t)NE*4;
  int* soff    = (int*)p;     p += (size_t)(NRR+8)*4;
  int* bincnt  = (int*)p;     p += 128*4;
  int* binoff  = (int*)p;     p += 128*4;
  int* bincur  = (int*)p;     p += 128*4;
  __bf16* W1a  = (__bf16*)p;  p += 64*320*2;
  __bf16* W2a  = (__bf16*)p;  p += 128*128*2;
  __bf16* W1b  = (__bf16*)p;  p += 64*320*2;
  __bf16* W2b  = (__bf16*)p;  p += 128*128*2;
  float* B1a   = (float*)p;   p += 64*4;
  float* B2a   = (float*)p;   p += 128*4;
  float* B1b   = (float*)p;   p += 64*4;
  float* B2b   = (float*)p;   p += 128*4;

  float* out = (float*)d_out;

  // segment-level counting sort of edges (shared by both layers)
  hipMemsetAsync(bincnt, 0, 128*4, stream);
  binhist_kernel<<<64, 256, 0, stream>>>(dst, rel, bincnt);
  binscan_kernel<<<1, 64, 0, stream>>>(bincnt, binoff, bincur, soff);
  passA_kernel<<<(NE+8191)/8192, 256, 0, stream>>>(src, dst, rel, bincur, ebin);
  passB_kernel<<<NBIN, 1024, 0, stream>>>(ebin, binoff, soff, ebuck);

  tobf16_kernel<<<(NN*64/8 + 255)/256, 256, 0, stream>>>(x, xb);
  prep_kernel<<<80, 256, 0, stream>>>(c1w, c1b, c1ws, c1bs, h1pw, h1pb, h1tw, h1tb,
                                      W1a, W2a, B1a, B2a);
  prep_kernel<<<80, 256, 0, stream>>>(c2w, c2b, c2ws, c2bs, h2pw, h2pb, h2tw, h2tb,
                                      W1b, W2b, B1b, B2b);

  // layer 1
  gather_kernel<<<NRR/32, 256, 0, stream>>>(ebuck, soff, xb, segb);
  dense_kernel<true><<<(NN+127)/128, 256, 0, stream>>>(segb, xb, xb, W1a, W2a, B1a, B2a,
                                                       h1b, g1b, nullptr);
  // layer 2
  gather_kernel<<<NRR/32, 256, 0, stream>>>(ebuck, soff, g1b, segb);
  dense_kernel<false><<<(NN+127)/128, 256, 0, stream>>>(segb, g1b, h1b, W1b, W2b, B1b, B2b,
                                                        nullptr, nullptr, out);
}